// Round 9
// baseline (1031.312 us; speedup 1.0000x reference)
//
#include <hip/hip_runtime.h>
#include <math.h>

static constexpr int kN0  = 100000;
static constexpr int kN1  = 20000;
static constexpr int kN2  = 4000;
static constexpr int kDeg = 10;
static constexpr int kD   = 512;
static constexpr int kFF  = 2048;
static constexpr int kRows  = 48;  // rows per MFMA block (gemm)
static constexpr int kRowsN = 16;  // rows per MFMA block (node_h) -> 3 blocks/CU
static constexpr int kLdA  = 584;  // node_h LDS row stride (bf16 elems, +8 pad)
static constexpr int kLdG  = 520;  // gemm LDS row stride for 512-k chunk (+8 pad)

using short8  = __attribute__((ext_vector_type(8))) short;
using floatx4 = __attribute__((ext_vector_type(4))) float;

__device__ inline unsigned short f2bf(float f) {
    union { float f; unsigned u; } v; v.f = f;
    unsigned r = v.u + 0x7FFFu + ((v.u >> 16) & 1u);  // RNE
    return (unsigned short)(r >> 16);
}
__device__ inline float bf2f(ushort u) {
    union { unsigned v; float f; } x; x.v = (unsigned)u << 16; return x.f;
}

// ---------------------------------------------------------------------------
// Pack node_h weights (ee_w || proj_w, K padded to 576) into b-frag order.
// ---------------------------------------------------------------------------
__global__ __launch_bounds__(256) void pack_node_w_kernel(
    const float* __restrict__ ee_w, const float* __restrict__ proj_w,
    ushort* __restrict__ Bp)
{
    int tid  = blockIdx.x * 256 + threadIdx.x;   // 0 .. 36863
    int lane = tid & 63;
    int tile = tid >> 6;                          // kc*32 + ct
    int n     = (tile & 31) * 16 + (lane & 15);
    int kbase = (tile >> 5) * 32 + (lane >> 4) * 8;
    ushort v[8];
    #pragma unroll
    for (int j = 0; j < 8; ++j) {
        int k = kbase + j;
        float f = 0.f;
        if (k < 256)      f = ee_w[(size_t)n * 256 + k];
        else if (k < 556) f = proj_w[(size_t)n * 300 + (k - 256)];
        v[j] = f2bf(f);
    }
    uint4 u;
    u.x = (unsigned)v[0] | ((unsigned)v[1] << 16);
    u.y = (unsigned)v[2] | ((unsigned)v[3] << 16);
    u.z = (unsigned)v[4] | ((unsigned)v[5] << 16);
    u.w = (unsigned)v[6] | ((unsigned)v[7] << 16);
    *(uint4*)(Bp + (size_t)tid * 8) = u;
}

// ---------------------------------------------------------------------------
// Pack the 12 (512x512) attention weight matrices into b-frag order.
// ---------------------------------------------------------------------------
__global__ __launch_bounds__(256) void pack512_many_kernel(
    const float* __restrict__ sa_in_w, const float* __restrict__ sa_out_w,
    const float* __restrict__ ca_in_w, const float* __restrict__ ca_out_w,
    ushort* __restrict__ dst)
{
    int y = blockIdx.y, l = y / 6, m = y % 6;
    const float* W;
    switch (m) {
        case 0: W = sa_in_w  + (size_t)l * 3 * kD * kD + (size_t)2 * kD * kD; break;
        case 1: W = sa_out_w + (size_t)l * kD * kD; break;
        case 2: W = ca_in_w  + (size_t)l * 3 * kD * kD; break;
        case 3: W = ca_in_w  + (size_t)l * 3 * kD * kD + (size_t)kD * kD; break;
        case 4: W = ca_in_w  + (size_t)l * 3 * kD * kD + (size_t)2 * kD * kD; break;
        default:W = ca_out_w + (size_t)l * kD * kD; break;
    }
    int tid  = blockIdx.x * 256 + threadIdx.x;   // 0..32767
    int lane = tid & 63;
    int tile = tid >> 6;                          // kc*32+ct
    int n  = (tile & 31) * 16 + (lane & 15);
    int kb = (tile >> 5) * 32 + (lane >> 4) * 8;
    const float* src = W + (size_t)n * 512 + kb;
    ushort v[8];
    #pragma unroll
    for (int j = 0; j < 8; ++j) v[j] = f2bf(src[j]);
    uint4 u;
    u.x = (unsigned)v[0] | ((unsigned)v[1] << 16);
    u.y = (unsigned)v[2] | ((unsigned)v[3] << 16);
    u.z = (unsigned)v[4] | ((unsigned)v[5] << 16);
    u.w = (unsigned)v[6] | ((unsigned)v[7] << 16);
    *(uint4*)(dst + (size_t)y * 262144 + (size_t)tid * 8) = u;
}

// Generic pack: W is (N x K) row-major; blockIdx.y selects matrix.
__global__ __launch_bounds__(256) void pack_generic_kernel(
    const float* __restrict__ src, size_t srcStride,
    ushort* __restrict__ dst, size_t dstStride, int N, int K)
{
    int tid  = blockIdx.x * 256 + threadIdx.x;
    int NT = N >> 4;
    int lane = tid & 63;
    int tile = tid >> 6;
    int ct = tile % NT, kc = tile / NT;
    int n  = ct * 16 + (lane & 15);
    int kb = kc * 32 + (lane >> 4) * 8;
    const float* W = src + blockIdx.y * srcStride + (size_t)n * K + kb;
    ushort v[8];
    #pragma unroll
    for (int j = 0; j < 8; ++j) v[j] = f2bf(W[j]);
    uint4 u;
    u.x = (unsigned)v[0] | ((unsigned)v[1] << 16);
    u.y = (unsigned)v[2] | ((unsigned)v[3] << 16);
    u.z = (unsigned)v[4] | ((unsigned)v[5] << 16);
    u.w = (unsigned)v[6] | ((unsigned)v[7] << 16);
    *(uint4*)(dst + blockIdx.y * dstStride + (size_t)tid * 8) = u;
}

// ---------------------------------------------------------------------------
// MFMA node_h — merged 3-segment dispatch, 16 rows/block, 3 blocks/CU.
// acc = 4 floatx4 = 16 regs; unified ~76/wave -> (512,6) = 6 waves/SIMD.
// ---------------------------------------------------------------------------
__global__ __launch_bounds__(512, 6) void node_h_mfma(
    const int* __restrict__ nid0a, const float* __restrict__ content0a,
    ushort* __restrict__ outB0, int n0,
    const int* __restrict__ nid1a, const float* __restrict__ content1a,
    ushort* __restrict__ outB1, int n1,
    const int* __restrict__ nid2a, const float* __restrict__ content2a,
    ushort* __restrict__ outB2, float* __restrict__ outF2, int n2,
    const float* __restrict__ node_emb_w,
    const ushort* __restrict__ Bp,
    const float* __restrict__ ee_b, const float* __restrict__ proj_b,
    const float* __restrict__ proj_g, const float* __restrict__ proj_beta)
{
    __shared__ __align__(16) ushort As[kRowsN * kLdA];        // 18688 B
    __shared__ float redS[8][kRowsN], redQ[8][kRowsN];
    __shared__ float meanv[kRowsN], rstdv[kRowsN], rowinv[kRowsN];

    const int t    = threadIdx.x;
    const int lane = t & 63;
    const int wv   = t >> 6;
    const int quad = lane >> 4;
    const int l15  = lane & 15;

    const int g0 = (n0 + kRowsN - 1) / kRowsN;
    const int g1 = (n1 + kRowsN - 1) / kRowsN;
    int bx = blockIdx.x;
    const int* nid; const float* content; ushort* outB; float* outF = nullptr;
    int ldh, n;
    if (bx < g0)           { nid = nid0a; content = content0a; outB = outB0; ldh = 512;  n = n0; }
    else if (bx < g0 + g1) { bx -= g0; nid = nid1a; content = content1a; outB = outB1; ldh = 1024; n = n1; }
    else                   { bx -= g0 + g1; nid = nid2a; content = content2a; outB = outB2; outF = outF2; ldh = 512; n = n2; }
    const int row0 = bx * kRowsN;

    // stage 16 rows x 576 cols (emb 256 | content 300 | pad) fp32->bf16
    // 16*144 = 2304 float4 slots
    #pragma unroll
    for (int it = 0; it < 5; ++it) {
        int flat = it * 512 + t;
        if (flat < kRowsN * 144) {
            int r  = flat / 144;
            int k4 = flat - r * 144;
            int row = row0 + r; if (row >= n) row = n - 1;
            float4 f = make_float4(0.f, 0.f, 0.f, 0.f);
            if (k4 < 64)
                f = *(const float4*)(node_emb_w + ((size_t)(nid[row] + 1)) * 256 + k4 * 4);
            else if (k4 < 139)
                f = *(const float4*)(content + (size_t)row * 300 + (k4 - 64) * 4);
            ushort4 o = make_ushort4(f2bf(f.x), f2bf(f.y), f2bf(f.z), f2bf(f.w));
            *(ushort4*)(As + (size_t)r * kLdA + k4 * 4) = o;
        }
    }
    __syncthreads();

    floatx4 acc[4] = {};
    const short8* BpV = (const short8*)Bp;

    // ---- phase 1: content @ proj_w^T  (kc 8..17) ----
    #pragma unroll
    for (int kc = 8; kc < 18; ++kc) {
        const short8* bp = BpV + (size_t)(kc * 32 + wv * 4) * 64 + lane;
        short8 b0 = bp[0], b1 = bp[64], b2 = bp[128], b3 = bp[192];
        short8 a = *(const short8*)(As + (size_t)l15 * kLdA + kc * 32 + quad * 8);
        acc[0] = __builtin_amdgcn_mfma_f32_16x16x32_bf16(a, b0, acc[0], 0, 0, 0);
        acc[1] = __builtin_amdgcn_mfma_f32_16x16x32_bf16(a, b1, acc[1], 0, 0, 0);
        acc[2] = __builtin_amdgcn_mfma_f32_16x16x32_bf16(a, b2, acc[2], 0, 0, 0);
        acc[3] = __builtin_amdgcn_mfma_f32_16x16x32_bf16(a, b3, acc[3], 0, 0, 0);
    }

    const int colbase = wv * 64 + l15;
    float pb[4], pg[4], pbt[4], eb[4];
    #pragma unroll
    for (int ct = 0; ct < 4; ++ct) {
        int c = colbase + ct * 16;
        pb[ct]  = proj_b[c];
        pg[ct]  = proj_g[c];
        pbt[ct] = proj_beta[c];
        eb[ct]  = ee_b[c];
    }

    // leaky + partial LN stats
    float s4[4], q4[4];
    #pragma unroll
    for (int i = 0; i < 4; ++i) {
        float s = 0.f, q = 0.f;
        #pragma unroll
        for (int ct = 0; ct < 4; ++ct) {
            float c = acc[ct][i] + pb[ct];
            c = (c >= 0.f) ? c : 0.1f * c;
            acc[ct][i] = c;
            s += c; q = fmaf(c, c, q);
        }
        s4[i] = s; q4[i] = q;
    }
    #pragma unroll
    for (int idx = 0; idx < 4; ++idx) {
        #pragma unroll
        for (int m = 1; m < 16; m <<= 1) {
            s4[idx] += __shfl_xor(s4[idx], m);
            q4[idx] += __shfl_xor(q4[idx], m);
        }
    }
    if (l15 == 0) {
        #pragma unroll
        for (int i = 0; i < 4; ++i) {
            int rl = quad * 4 + i;
            redS[wv][rl] = s4[i];
            redQ[wv][rl] = q4[i];
        }
    }
    __syncthreads();
    if (t < kRowsN) {
        float s = 0.f, q = 0.f;
        #pragma unroll
        for (int w = 0; w < 8; ++w) { s += redS[w][t]; q += redQ[w][t]; }
        float m   = s * (1.f / 512.f);
        float var = q * (1.f / 512.f) - m * m;
        meanv[t] = m;
        rstdv[t] = rsqrtf(var + 1e-5f);
    }
    __syncthreads();

    // acc := normalized-content + ee_b  (emb MFMAs accumulate on top)
    #pragma unroll
    for (int i = 0; i < 4; ++i) {
        int rl = quad * 4 + i;
        float m = meanv[rl], rs = rstdv[rl];
        #pragma unroll
        for (int ct = 0; ct < 4; ++ct)
            acc[ct][i] = (acc[ct][i] - m) * rs * pg[ct] + pbt[ct] + eb[ct];
    }

    // ---- phase 2: emb @ ee_w^T  (kc 0..7) ----
    #pragma unroll
    for (int kc = 0; kc < 8; ++kc) {
        const short8* bp = BpV + (size_t)(kc * 32 + wv * 4) * 64 + lane;
        short8 b0 = bp[0], b1 = bp[64], b2 = bp[128], b3 = bp[192];
        short8 a = *(const short8*)(As + (size_t)l15 * kLdA + kc * 32 + quad * 8);
        acc[0] = __builtin_amdgcn_mfma_f32_16x16x32_bf16(a, b0, acc[0], 0, 0, 0);
        acc[1] = __builtin_amdgcn_mfma_f32_16x16x32_bf16(a, b1, acc[1], 0, 0, 0);
        acc[2] = __builtin_amdgcn_mfma_f32_16x16x32_bf16(a, b2, acc[2], 0, 0, 0);
        acc[3] = __builtin_amdgcn_mfma_f32_16x16x32_bf16(a, b3, acc[3], 0, 0, 0);
    }

    // ---- row norm ----
    #pragma unroll
    for (int i = 0; i < 4; ++i) {
        float psq = 0.f;
        #pragma unroll
        for (int ct = 0; ct < 4; ++ct)
            psq = fmaf(acc[ct][i], acc[ct][i], psq);
        q4[i] = psq;
    }
    #pragma unroll
    for (int idx = 0; idx < 4; ++idx)
        #pragma unroll
        for (int m = 1; m < 16; m <<= 1)
            q4[idx] += __shfl_xor(q4[idx], m);
    if (l15 == 0) {
        #pragma unroll
        for (int i = 0; i < 4; ++i)
            redS[wv][quad * 4 + i] = q4[i];
    }
    __syncthreads();
    if (t < kRowsN) {
        float s = 0.f;
        #pragma unroll
        for (int w = 0; w < 8; ++w) s += redS[w][t];
        rowinv[t] = 1.f / fmaxf(sqrtf(s), 1e-5f);
    }
    __syncthreads();

    #pragma unroll
    for (int i = 0; i < 4; ++i) {
        int rl = quad * 4 + i;
        int grow = row0 + rl;
        if (grow < n) {
            float inv = rowinv[rl];
            ushort* dB = outB + (size_t)grow * ldh + colbase;
            #pragma unroll
            for (int ct = 0; ct < 4; ++ct) {
                float v = acc[ct][i] * inv;
                dB[ct * 16] = f2bf(v);
                if (outF) outF[(size_t)grow * ldh + colbase + ct * 16] = v;
            }
        }
    }
}

// ---------------------------------------------------------------------------
// MFMA GEMM, bf16 A-operand. EPI: 0=plain->bf16  1=gelu->bf16
// 2=residual(fp32)+LayerNorm -> fp32 Cf AND bf16 Cb
// 3=EPI2 then second GEMM from LDS-resident LN output: C2 = LN(..)@Bp2^T+bias2
// ---------------------------------------------------------------------------
__device__ inline float gelu_exact(float x) {
    return 0.5f * x * (1.f + erff(x * 0.70710678118654752f));
}

template<int EPI>
__global__ __launch_bounds__(512, 2) void gemm_mfma(
    const ushort* __restrict__ A, int lda,
    const ushort* __restrict__ Bp, const float* __restrict__ bias,
    ushort* __restrict__ Cb, float* __restrict__ Cf, int ldc,
    const float* __restrict__ resid,
    const float* __restrict__ lng, const float* __restrict__ lnb,
    int M, int K, int N,
    const ushort* __restrict__ Bp2, const float* __restrict__ bias2,
    ushort* __restrict__ C2)
{
    __shared__ __align__(16) ushort As[kRows * kLdG];      // 49920 B
    __shared__ float redS[8][kRows], redQ[8][kRows];
    __shared__ float meanv[kRows], rstdv[kRows];

    const int t    = threadIdx.x;
    const int lane = t & 63;
    const int wv   = t >> 6;
    const int quad = lane >> 4;
    const int l15  = lane & 15;
    const int row0 = blockIdx.x * kRows;
    const int nb   = blockIdx.y;
    const int NT   = N >> 4;

    floatx4 acc[3][4] = {};
    const short8* BpV = (const short8*)Bp;

    for (int k0 = 0; k0 < K; k0 += 512) {
        // stage A chunk (48 x 512) bf16 direct: 3072 x 16B slots = 6*512
        #pragma unroll
        for (int it = 0; it < 6; ++it) {
            int flat = it * 512 + t;
            int r  = flat >> 6;          // 64 slots per row
            int k8 = flat & 63;
            int row = row0 + r; if (row >= M) row = M - 1;
            short8 v = *(const short8*)(A + (size_t)row * lda + k0 + k8 * 8);
            *(short8*)(As + (size_t)r * kLdG + k8 * 8) = v;
        }
        __syncthreads();
        const int g0 = k0 >> 5;
        #pragma unroll
        for (int kc = 0; kc < 16; ++kc) {
            const short8* bp = BpV + ((size_t)(g0 + kc) * NT + nb * 32 + wv * 4) * 64 + lane;
            short8 b0 = bp[0], b1 = bp[64], b2 = bp[128], b3 = bp[192];
            short8 a[3];
            #pragma unroll
            for (int rt = 0; rt < 3; ++rt)
                a[rt] = *(const short8*)(As + (size_t)(rt * 16 + l15) * kLdG + kc * 32 + quad * 8);
            #pragma unroll
            for (int rt = 0; rt < 3; ++rt) {
                acc[rt][0] = __builtin_amdgcn_mfma_f32_16x16x32_bf16(a[rt], b0, acc[rt][0], 0, 0, 0);
                acc[rt][1] = __builtin_amdgcn_mfma_f32_16x16x32_bf16(a[rt], b1, acc[rt][1], 0, 0, 0);
                acc[rt][2] = __builtin_amdgcn_mfma_f32_16x16x32_bf16(a[rt], b2, acc[rt][2], 0, 0, 0);
                acc[rt][3] = __builtin_amdgcn_mfma_f32_16x16x32_bf16(a[rt], b3, acc[rt][3], 0, 0, 0);
            }
        }
        __syncthreads();
    }

    const int colloc = wv * 64 + l15;           // 0..511 within col-block
    float b[4];
    #pragma unroll
    for (int ct = 0; ct < 4; ++ct) b[ct] = bias[nb * 512 + colloc + ct * 16];

    if constexpr (EPI == 0 || EPI == 1) {
        #pragma unroll
        for (int rt = 0; rt < 3; ++rt) {
            #pragma unroll
            for (int i = 0; i < 4; ++i) {
                int row = row0 + rt * 16 + quad * 4 + i;
                if (row < M) {
                    ushort* dst = Cb + (size_t)row * ldc + nb * 512 + colloc;
                    #pragma unroll
                    for (int ct = 0; ct < 4; ++ct) {
                        float v = acc[rt][ct][i] + b[ct];
                        if (EPI == 1) v = gelu_exact(v);
                        dst[ct * 16] = f2bf(v);
                    }
                }
            }
        }
    } else {
        float lg[4], lb[4];
        #pragma unroll
        for (int ct = 0; ct < 4; ++ct) {
            lg[ct] = lng[colloc + ct * 16];
            lb[ct] = lnb[colloc + ct * 16];
        }
        float s12[12], q12[12];
        #pragma unroll
        for (int rt = 0; rt < 3; ++rt) {
            #pragma unroll
            for (int i = 0; i < 4; ++i) {
                int rl = rt * 16 + quad * 4 + i;
                int row = row0 + rl; if (row >= M) row = M - 1;
                const float* rr = resid + (size_t)row * 512 + colloc;
                float s = 0.f, q = 0.f;
                #pragma unroll
                for (int ct = 0; ct < 4; ++ct) {
                    float h = acc[rt][ct][i] + b[ct] + rr[ct * 16];
                    acc[rt][ct][i] = h;
                    s += h; q = fmaf(h, h, q);
                }
                s12[rt * 4 + i] = s; q12[rt * 4 + i] = q;
            }
        }
        #pragma unroll
        for (int idx = 0; idx < 12; ++idx) {
            #pragma unroll
            for (int m = 1; m < 16; m <<= 1) {
                s12[idx] += __shfl_xor(s12[idx], m);
                q12[idx] += __shfl_xor(q12[idx], m);
            }
        }
        if (l15 == 0) {
            #pragma unroll
            for (int rt = 0; rt < 3; ++rt)
                #pragma unroll
                for (int i = 0; i < 4; ++i) {
                    int rl = rt * 16 + quad * 4 + i;
                    redS[wv][rl] = s12[rt * 4 + i];
                    redQ[wv][rl] = q12[rt * 4 + i];
                }
        }
        __syncthreads();
        if (t < kRows) {
            float s = 0.f, q = 0.f;
            #pragma unroll
            for (int w = 0; w < 8; ++w) { s += redS[w][t]; q += redQ[w][t]; }
            float m   = s * (1.f / 512.f);
            float var = q * (1.f / 512.f) - m * m;
            meanv[t] = m;
            rstdv[t] = rsqrtf(var + 1e-5f);
        }
        __syncthreads();
        #pragma unroll
        for (int rt = 0; rt < 3; ++rt) {
            #pragma unroll
            for (int i = 0; i < 4; ++i) {
                int rl = rt * 16 + quad * 4 + i;
                int row = row0 + rl;
                if (row < M) {
                    float m = meanv[rl], rs = rstdv[rl];
                    float*  dF = Cf + (size_t)row * 512 + colloc;
                    ushort* dB = Cb + (size_t)row * 512 + colloc;
                    #pragma unroll
                    for (int ct = 0; ct < 4; ++ct) {
                        float v = (acc[rt][ct][i] - m) * rs * lg[ct] + lb[ct];
                        dF[ct * 16] = v;
                        dB[ct * 16] = f2bf(v);
                        if (EPI == 3)
                            As[(size_t)rl * kLdG + colloc + ct * 16] = f2bf(v);
                    }
                }
            }
        }
        if constexpr (EPI == 3) {
            // second GEMM: C2 = LN_output @ Bp2^T + bias2  (K=512, N=512)
            __syncthreads();
            floatx4 acc2[3][4] = {};
            const short8* Bp2V = (const short8*)Bp2;
            #pragma unroll
            for (int kc = 0; kc < 16; ++kc) {
                const short8* bp = Bp2V + ((size_t)kc * 32 + wv * 4) * 64 + lane;
                short8 b0 = bp[0], b1 = bp[64], b2 = bp[128], b3 = bp[192];
                short8 a[3];
                #pragma unroll
                for (int rt = 0; rt < 3; ++rt)
                    a[rt] = *(const short8*)(As + (size_t)(rt * 16 + l15) * kLdG + kc * 32 + quad * 8);
                #pragma unroll
                for (int rt = 0; rt < 3; ++rt) {
                    acc2[rt][0] = __builtin_amdgcn_mfma_f32_16x16x32_bf16(a[rt], b0, acc2[rt][0], 0, 0, 0);
                    acc2[rt][1] = __builtin_amdgcn_mfma_f32_16x16x32_bf16(a[rt], b1, acc2[rt][1], 0, 0, 0);
                    acc2[rt][2] = __builtin_amdgcn_mfma_f32_16x16x32_bf16(a[rt], b2, acc2[rt][2], 0, 0, 0);
                    acc2[rt][3] = __builtin_amdgcn_mfma_f32_16x16x32_bf16(a[rt], b3, acc2[rt][3], 0, 0, 0);
                }
            }
            float b2[4];
            #pragma unroll
            for (int ct = 0; ct < 4; ++ct) b2[ct] = bias2[colloc + ct * 16];
            #pragma unroll
            for (int rt = 0; rt < 3; ++rt) {
                #pragma unroll
                for (int i = 0; i < 4; ++i) {
                    int row = row0 + rt * 16 + quad * 4 + i;
                    if (row < M) {
                        ushort* dst = C2 + (size_t)row * 512 + colloc;
                        #pragma unroll
                        for (int ct = 0; ct < 4; ++ct)
                            dst[ct * 16] = f2bf(acc2[rt][ct][i] + b2[ct]);
                    }
                }
            }
        }
    }
}

// ---------------------------------------------------------------------------
// Merged 5-way GEMM (all K=512, N=512, bf16 A, bf16 C, plain epilogue).
// ---------------------------------------------------------------------------
__global__ __launch_bounds__(512, 2) void gemm5_mfma(
    const ushort* __restrict__ A0, const ushort* __restrict__ B0w,
    const float* __restrict__ b0p, ushort* __restrict__ C0, int M0,
    const ushort* __restrict__ A1, const ushort* __restrict__ B1w,
    const float* __restrict__ b1p, ushort* __restrict__ C1, int M1,
    const ushort* __restrict__ A2, const ushort* __restrict__ B2w,
    const float* __restrict__ b2p, ushort* __restrict__ C2, int M2,
    const ushort* __restrict__ A3, const ushort* __restrict__ B3w,
    const float* __restrict__ b3p, ushort* __restrict__ C3, int M3,
    const ushort* __restrict__ A4, const ushort* __restrict__ B4w,
    const float* __restrict__ b4p, ushort* __restrict__ C4, int M4)
{
    __shared__ __align__(16) ushort As[kRows * kLdG];

    const int t    = threadIdx.x;
    const int lane = t & 63;
    const int wv   = t >> 6;
    const int quad = lane >> 4;
    const int l15  = lane & 15;

    const int g0 = (M0 + kRows - 1) / kRows;
    const int g1 = (M1 + kRows - 1) / kRows;
    const int g2 = (M2 + kRows - 1) / kRows;
    const int g3 = (M3 + kRows - 1) / kRows;
    int bx = blockIdx.x;
    const ushort* A; const ushort* Bw; const float* bias; ushort* C; int M;
    if (bx < g0)                { A = A0; Bw = B0w; bias = b0p; C = C0; M = M0; }
    else if (bx < g0+g1)        { bx -= g0;       A = A1; Bw = B1w; bias = b1p; C = C1; M = M1; }
    else if (bx < g0+g1+g2)     { bx -= g0+g1;    A = A2; Bw = B2w; bias = b2p; C = C2; M = M2; }
    else if (bx < g0+g1+g2+g3)  { bx -= g0+g1+g2; A = A3; Bw = B3w; bias = b3p; C = C3; M = M3; }
    else                        { bx -= g0+g1+g2+g3; A = A4; Bw = B4w; bias = b4p; C = C4; M = M4; }
    const int row0 = bx * kRows;

    floatx4 acc[3][4] = {};
    const short8* BpV = (const short8*)Bw;

    #pragma unroll
    for (int it = 0; it < 6; ++it) {
        int flat = it * 512 + t;
        int r  = flat >> 6;
        int k8 = flat & 63;
        int row = row0 + r; if (row >= M) row = M - 1;
        short8 v = *(const short8*)(A + (size_t)row * 512 + k8 * 8);
        *(short8*)(As + (size_t)r * kLdG + k8 * 8) = v;
    }
    __syncthreads();
    #pragma unroll
    for (int kc = 0; kc < 16; ++kc) {
        const short8* bp = BpV + ((size_t)kc * 32 + wv * 4) * 64 + lane;
        short8 b0 = bp[0], b1 = bp[64], b2 = bp[128], b3 = bp[192];
        short8 a[3];
        #pragma unroll
        for (int rt = 0; rt < 3; ++rt)
            a[rt] = *(const short8*)(As + (size_t)(rt * 16 + l15) * kLdG + kc * 32 + quad * 8);
        #pragma unroll
        for (int rt = 0; rt < 3; ++rt) {
            acc[rt][0] = __builtin_amdgcn_mfma_f32_16x16x32_bf16(a[rt], b0, acc[rt][0], 0, 0, 0);
            acc[rt][1] = __builtin_amdgcn_mfma_f32_16x16x32_bf16(a[rt], b1, acc[rt][1], 0, 0, 0);
            acc[rt][2] = __builtin_amdgcn_mfma_f32_16x16x32_bf16(a[rt], b2, acc[rt][2], 0, 0, 0);
            acc[rt][3] = __builtin_amdgcn_mfma_f32_16x16x32_bf16(a[rt], b3, acc[rt][3], 0, 0, 0);
        }
    }

    const int colloc = wv * 64 + l15;
    float b[4];
    #pragma unroll
    for (int ct = 0; ct < 4; ++ct) b[ct] = bias[colloc + ct * 16];
    #pragma unroll
    for (int rt = 0; rt < 3; ++rt) {
        #pragma unroll
        for (int i = 0; i < 4; ++i) {
            int row = row0 + rt * 16 + quad * 4 + i;
            if (row < M) {
                ushort* dst = C + (size_t)row * 512 + colloc;
                #pragma unroll
                for (int ct = 0; ct < 4; ++ct)
                    dst[ct * 16] = f2bf(acc[rt][ct][i] + b[ct]);
            }
        }
    }
}

// ---------------------------------------------------------------------------
__device__ inline float block_sum256(float v, float* red4) {
    #pragma unroll
    for (int off = 32; off > 0; off >>= 1) v += __shfl_down(v, off);
    if ((threadIdx.x & 63) == 0) red4[threadIdx.x >> 6] = v;
    __syncthreads();
    return red4[0] + red4[1] + red4[2] + red4[3];
}

__global__ __launch_bounds__(256) void agg_norm1_kernel(
    const ushort* __restrict__ h0, const int* __restrict__ esrc,
    ushort* __restrict__ h1cat)
{
    __shared__ int idx[kDeg];
    __shared__ float red4[4];
    int i = blockIdx.x, t = threadIdx.x;
    if (t < kDeg) idx[t] = esrc[i * kDeg + t];
    __syncthreads();
    float s0 = 0.f, s1 = 0.f;
    for (int e = 0; e < kDeg; ++e) {
        const ushort* hr = h0 + (size_t)idx[e] * 512;
        s0 += bf2f(hr[t]); s1 += bf2f(hr[t + 256]);
    }
    s0 *= 0.1f; s1 *= 0.1f;
    size_t base = (size_t)i * 1024;
    float o0 = bf2f(h1cat[base + 512 + t]);
    float o1 = bf2f(h1cat[base + 768 + t]);
    float tot = block_sum256(s0 * s0 + s1 * s1 + o0 * o0 + o1 * o1, red4);
    float inv = 1.f / fmaxf(sqrtf(tot), 1e-5f);
    h1cat[base + t]       = f2bf(s0 * inv);
    h1cat[base + 256 + t] = f2bf(s1 * inv);
    h1cat[base + 512 + t] = f2bf(o0 * inv);
    h1cat[base + 768 + t] = f2bf(o1 * inv);
}

__global__ __launch_bounds__(256) void agg2_kernel(
    const ushort* __restrict__ h1cat, const int* __restrict__ esrc,
    ushort* __restrict__ m2)
{
    __shared__ int idx[kDeg];
    int i = blockIdx.x, t = threadIdx.x;
    if (t < kDeg) idx[t] = esrc[i * kDeg + t];
    __syncthreads();
    float s0 = 0.f, s1 = 0.f, s2 = 0.f, s3 = 0.f;
    for (int e = 0; e < kDeg; ++e) {
        const ushort* hr = h1cat + (size_t)idx[e] * 1024;
        s0 += bf2f(hr[t]);       s1 += bf2f(hr[t + 256]);
        s2 += bf2f(hr[t + 512]); s3 += bf2f(hr[t + 768]);
    }
    size_t base = (size_t)i * 1024;
    m2[base + t]       = f2bf(s0 * 0.1f);
    m2[base + 256 + t] = f2bf(s1 * 0.1f);
    m2[base + 512 + t] = f2bf(s2 * 0.1f);
    m2[base + 768 + t] = f2bf(s3 * 0.1f);
}

// Kb/Vb rows: 2i = memory slot 0, 2i+1 = slot 1 (m2 viewed as (2*N2, 512)).
__global__ __launch_bounds__(256) void attn_combine_kernel(
    const ushort* __restrict__ Q,
    const ushort* __restrict__ Kb, const ushort* __restrict__ Vb,
    ushort* __restrict__ O)
{
    __shared__ float red[4][4];
    __shared__ float a[4];
    int i = blockIdx.x, t = threadIdx.x;
    size_t base  = (size_t)i * 512;
    size_t base0 = (size_t)(2 * i) * 512;
    size_t base1 = base0 + 512;
    float q0 = bf2f(Q[base + t]), q1 = bf2f(Q[base + t + 256]);
    float p00 = q0 * bf2f(Kb[base0 + t]);
    float p01 = q0 * bf2f(Kb[base1 + t]);
    float p10 = q1 * bf2f(Kb[base0 + t + 256]);
    float p11 = q1 * bf2f(Kb[base1 + t + 256]);
    #pragma unroll
    for (int off = 32; off > 0; off >>= 1) {
        p00 += __shfl_down(p00, off);
        p01 += __shfl_down(p01, off);
        p10 += __shfl_down(p10, off);
        p11 += __shfl_down(p11, off);
    }
    int w = t >> 6;
    if ((t & 63) == 0) { red[w][0] = p00; red[w][1] = p01; red[w][2] = p10; red[w][3] = p11; }
    __syncthreads();
    if (t == 0) {
        float s00 = (red[0][0] + red[1][0] + red[2][0] + red[3][0]) * 0.0625f;
        float s01 = (red[0][1] + red[1][1] + red[2][1] + red[3][1]) * 0.0625f;
        float s10 = (red[0][2] + red[1][2] + red[2][2] + red[3][2]) * 0.0625f;
        float s11 = (red[0][3] + red[1][3] + red[2][3] + red[3][3]) * 0.0625f;
        float m0 = fmaxf(s00, s01);
        float e0 = expf(s00 - m0), e1 = expf(s01 - m0);
        float d0 = e0 + e1;
        a[0] = e0 / d0; a[1] = e1 / d0;
        float m1 = fmaxf(s10, s11);
        float f0 = expf(s10 - m1), f1 = expf(s11 - m1);
        float d1 = f0 + f1;
        a[2] = f0 / d1; a[3] = f1 / d1;
    }
    __syncthreads();
    O[base + t]       = f2bf(a[0] * bf2f(Vb[base0 + t])       + a[1] * bf2f(Vb[base1 + t]));
    O[base + t + 256] = f2bf(a[2] * bf2f(Vb[base0 + t + 256]) + a[3] * bf2f(Vb[base1 + t + 256]));
}

__global__ __launch_bounds__(256) void final_norm_kernel(
    const float* __restrict__ tgt, float* __restrict__ out)
{
    __shared__ float red4[4];
    int i = blockIdx.x, t = threadIdx.x;
    size_t base = (size_t)i * 512;
    float v0 = tgt[base + t], v1 = tgt[base + t + 256];
    float tot = block_sum256(v0 * v0 + v1 * v1, red4);
    float inv = 1.f / fmaxf(sqrtf(tot), 1e-5f);
    out[base + t]       = v0 * inv;
    out[base + t + 256] = v1 * inv;
}

// ---------------------------------------------------------------------------
extern "C" void kernel_launch(void* const* d_in, const int* in_sizes, int n_in,
                              void* d_out, int out_size, void* d_ws, size_t ws_size,
                              hipStream_t stream)
{
    (void)in_sizes; (void)n_in; (void)out_size; (void)ws_size;
    const int*   nid0       = (const int*)d_in[0];
    const int*   nid1       = (const int*)d_in[1];
    const int*   nid2       = (const int*)d_in[2];
    const int*   esrc0      = (const int*)d_in[3];
    const int*   esrc1      = (const int*)d_in[5];
    const float* content0   = (const float*)d_in[7];
    const float* content1   = (const float*)d_in[8];
    const float* content2   = (const float*)d_in[9];
    const float* node_emb_w = (const float*)d_in[10];
    const float* ee_w       = (const float*)d_in[11];
    const float* ee_b       = (const float*)d_in[12];
    const float* proj_w     = (const float*)d_in[13];
    const float* proj_b     = (const float*)d_in[14];
    const float* proj_g     = (const float*)d_in[15];
    const float* proj_beta  = (const float*)d_in[16];
    const float* sa_in_w    = (const float*)d_in[17];
    const float* sa_in_b    = (const float*)d_in[18];
    const float* sa_out_w   = (const float*)d_in[19];
    const float* sa_out_b   = (const float*)d_in[20];
    const float* ca_in_w    = (const float*)d_in[21];
    const float* ca_in_b    = (const float*)d_in[22];
    const float* ca_out_w   = (const float*)d_in[23];
    const float* ca_out_b   = (const float*)d_in[24];
    const float* lin1_w     = (const float*)d_in[25];
    const float* lin1_b     = (const float*)d_in[26];
    const float* lin2_w     = (const float*)d_in[27];
    const float* lin2_b     = (const float*)d_in[28];
    const float* n1_g       = (const float*)d_in[29];
    const float* n1_b       = (const float*)d_in[30];
    const float* n2_g       = (const float*)d_in[31];
    const float* n2_b       = (const float*)d_in[32];
    const float* n3_g       = (const float*)d_in[33];
    const float* n3_b       = (const float*)d_in[34];

    float* ws = (float*)d_ws;
    size_t off = 0;
    ushort* h0b    = (ushort*)(ws + off); off += (size_t)kN0 * 512 / 2;
    ushort* h1catb = (ushort*)(ws + off); off += (size_t)kN1 * 1024 / 2;
    ushort* m2b    = (ushort*)(ws + off); off += (size_t)kN2 * 1024 / 2;
    float*  tgt    = ws + off;            off += (size_t)kN2 * 512;
    ushort* tgtb   = (ushort*)(ws + off); off += (size_t)kN2 * 512 / 2;
    ushort* Qbb    = (ushort*)(ws + off); off += (size_t)kN2 * 512 / 2;
    ushort* Kb0    = (ushort*)(ws + off); off += (size_t)2 * kN2 * 512 / 2;
    ushort* Vb0    = (ushort*)(ws + off); off += (size_t)2 * kN2 * 512 / 2;
    ushort* Kb1    = (ushort*)(ws + off); off += (size_t)2 * kN2 * 512 / 2;
    ushort* Vb1    = (ushort*)(ws + off); off += (size_t)2 * kN2 * 512 / 2;
    ushort* Obb    = (ushort*)(ws + off); off += (size_t)kN2 * 512 / 2;
    ushort* ffhb   = (ushort*)(ws + off); off += (size_t)kN2 * 2048 / 2;
    ushort* BpNode = (ushort*)(ws + off); off += 147456;           // 576*64*8 bf16
    ushort* Pw512  = (ushort*)(ws + off); off += 12 * 262144 / 2;  // 12 x 512x512
    ushort* Pl1    = (ushort*)(ws + off); off += 2 * 1048576 / 2;  // 2 x 2048x512
    ushort* Pl2    = (ushort*)(ws + off); off += 2 * 1048576 / 2;  // 2 x 512x2048

    dim3 blk(256);

    // ---- weight packing (4 launches) ----
    pack_node_w_kernel<<<dim3(144), blk, 0, stream>>>(ee_w, proj_w, BpNode);
    pack512_many_kernel<<<dim3(128, 12), blk, 0, stream>>>(
        sa_in_w, sa_out_w, ca_in_w, ca_out_w, Pw512);
    pack_generic_kernel<<<dim3(512, 2), blk, 0, stream>>>(
        lin1_w, (size_t)kFF * kD, Pl1, 1048576, kFF, kD);
    pack_generic_kernel<<<dim3(512, 2), blk, 0, stream>>>(
        lin2_w, (size_t)kD * kFF, Pl2, 1048576, kD, kFF);

    // ---- node_h (merged 3-segment dispatch, 16 rows/block, 3 blocks/CU) ----
    {
        int g0 = (kN0 + kRowsN - 1) / kRowsN;   // 6250
        int g1 = (kN1 + kRowsN - 1) / kRowsN;   // 1250
        int g2 = (kN2 + kRowsN - 1) / kRowsN;   // 250
        node_h_mfma<<<dim3(g0 + g1 + g2), dim3(512), 0, stream>>>(
            nid0, content0, h0b, kN0,
            nid1, content1, h1catb + 512, kN1,
            nid2, content2, tgtb, tgt, kN2,
            node_emb_w, BpNode, ee_b, proj_b, proj_g, proj_beta);
    }

    agg_norm1_kernel<<<dim3(kN1), blk, 0, stream>>>(h0b, esrc0, h1catb);
    agg2_kernel<<<dim3(kN2), blk, 0, stream>>>(h1catb, esrc1, m2b);

    const int M   = kN2;
    const int gM  = (M + kRows - 1) / kRows;       // 84
    const int gM2 = (2 * M + kRows - 1) / kRows;   // 167
    dim3 blk512(512);

    // ---- upfront: sa_v(l=0) + K/V for BOTH layers (all from m2b/tgtb) ----
    gemm5_mfma<<<dim3(gM + 4 * gM2), blk512, 0, stream>>>(
        tgtb, Pw512 + (size_t)0 * 262144, sa_in_b + 2 * kD,              Qbb, M,
        m2b,  Pw512 + (size_t)3 * 262144, ca_in_b + kD,                  Kb0, 2 * M,
        m2b,  Pw512 + (size_t)4 * 262144, ca_in_b + 2 * kD,              Vb0, 2 * M,
        m2b,  Pw512 + (size_t)9 * 262144, ca_in_b + 3 * kD + kD,         Kb1, 2 * M,
        m2b,  Pw512 + (size_t)10 * 262144, ca_in_b + 3 * kD + 2 * kD,    Vb1, 2 * M);

    for (int l = 0; l < 2; ++l) {
        const ushort* sa_out_p = Pw512 + (size_t)(l * 6 + 1) * 262144;
        const ushort* ca_q_p   = Pw512 + (size_t)(l * 6 + 2) * 262144;
        const ushort* ca_out_p = Pw512 + (size_t)(l * 6 + 5) * 262144;
        const ushort* l1_p     = Pl1 + (size_t)l * 1048576;
        const ushort* l2_p     = Pl2 + (size_t)l * 1048576;
        const float* saob = sa_out_b + (size_t)l * kD;
        const float* ca_b = ca_in_b + (size_t)l * 3 * kD;
        const float* caob = ca_out_b + (size_t)l * kD;
        const float* l1b = lin1_b + (size_t)l * kFF;
        const float* l2b = lin2_b + (size_t)l * kD;
        const ushort* Kb_l = (l == 0) ? Kb0 : Kb1;
        const ushort* Vb_l = (l == 0) ? Vb0 : Vb1;

        // fused: sa_out + LN1 -> tgt/tgtb, then ca_q -> Qbb (from LDS LN out)
        gemm_mfma<3><<<dim3(gM, 1), blk512, 0, stream>>>(
            Qbb, 512, sa_out_p, saob, tgtb, tgt, 512,
            tgt, n1_g + l * kD, n1_b + l * kD, M, 512, 512,
            ca_q_p, ca_b, Qbb);

        attn_combine_kernel<<<dim3(M), blk, 0, stream>>>(Qbb, Kb_l, Vb_l, Obb);

        gemm_mfma<2><<<dim3(gM, 1), blk512, 0, stream>>>(
            Obb, 512, ca_out_p, caob, tgtb, tgt, 512,
            tgt, n2_g + l * kD, n2_b + l * kD, M, 512, 512,
            nullptr, nullptr, nullptr);

        gemm_mfma<1><<<dim3(gM, 4), blk512, 0, stream>>>(
            tgtb, 512, l1_p, l1b, ffhb, nullptr, 2048,
            nullptr, nullptr, nullptr, M, 512, 2048,
            nullptr, nullptr, nullptr);

        if (l == 0) {
            // fused: ff2 + LN3 -> tgt/tgtb, then sa_v(l=1) -> Qbb
            gemm_mfma<3><<<dim3(gM, 1), blk512, 0, stream>>>(
                ffhb, 2048, l2_p, l2b, tgtb, tgt, 512,
                tgt, n3_g + l * kD, n3_b + l * kD, M, 2048, 512,
                Pw512 + (size_t)(6 + 0) * 262144, sa_in_b + 3 * kD + 2 * kD, Qbb);
        } else {
            gemm_mfma<2><<<dim3(gM, 1), blk512, 0, stream>>>(
                ffhb, 2048, l2_p, l2b, tgtb, tgt, 512,
                tgt, n3_g + l * kD, n3_b + l * kD, M, 2048, 512,
                nullptr, nullptr, nullptr);
        }
    }

    final_norm_kernel<<<dim3(kN2), blk, 0, stream>>>(tgt, (float*)d_out);
}

// Round 10
// 967.950 us; speedup vs baseline: 1.0655x; 1.0655x over previous
//
#include <hip/hip_runtime.h>
#include <math.h>

static constexpr int kN0  = 100000;
static constexpr int kN1  = 20000;
static constexpr int kN2  = 4000;
static constexpr int kDeg = 10;
static constexpr int kD   = 512;
static constexpr int kFF  = 2048;
static constexpr int kRows  = 48;  // rows per MFMA block (gemm)
static constexpr int kRowsN = 32;  // rows per MFMA block (node_h) -> 2 blocks/CU (empirical optimum)
static constexpr int kLdA  = 584;  // node_h LDS row stride (bf16 elems, +8 pad)
static constexpr int kLdG  = 520;  // gemm LDS row stride for 512-k chunk (+8 pad)

using short8  = __attribute__((ext_vector_type(8))) short;
using floatx4 = __attribute__((ext_vector_type(4))) float;

__device__ inline unsigned short f2bf(float f) {
    union { float f; unsigned u; } v; v.f = f;
    unsigned r = v.u + 0x7FFFu + ((v.u >> 16) & 1u);  // RNE
    return (unsigned short)(r >> 16);
}
__device__ inline float bf2f(ushort u) {
    union { unsigned v; float f; } x; x.v = (unsigned)u << 16; return x.f;
}

// ---------------------------------------------------------------------------
// Pack node_h weights (ee_w || proj_w, K padded to 576) into b-frag order.
// ---------------------------------------------------------------------------
__global__ __launch_bounds__(256) void pack_node_w_kernel(
    const float* __restrict__ ee_w, const float* __restrict__ proj_w,
    ushort* __restrict__ Bp)
{
    int tid  = blockIdx.x * 256 + threadIdx.x;   // 0 .. 36863
    int lane = tid & 63;
    int tile = tid >> 6;                          // kc*32 + ct
    int n     = (tile & 31) * 16 + (lane & 15);
    int kbase = (tile >> 5) * 32 + (lane >> 4) * 8;
    ushort v[8];
    #pragma unroll
    for (int j = 0; j < 8; ++j) {
        int k = kbase + j;
        float f = 0.f;
        if (k < 256)      f = ee_w[(size_t)n * 256 + k];
        else if (k < 556) f = proj_w[(size_t)n * 300 + (k - 256)];
        v[j] = f2bf(f);
    }
    uint4 u;
    u.x = (unsigned)v[0] | ((unsigned)v[1] << 16);
    u.y = (unsigned)v[2] | ((unsigned)v[3] << 16);
    u.z = (unsigned)v[4] | ((unsigned)v[5] << 16);
    u.w = (unsigned)v[6] | ((unsigned)v[7] << 16);
    *(uint4*)(Bp + (size_t)tid * 8) = u;
}

// ---------------------------------------------------------------------------
// Pack the 12 (512x512) attention weight matrices into b-frag order.
// ---------------------------------------------------------------------------
__global__ __launch_bounds__(256) void pack512_many_kernel(
    const float* __restrict__ sa_in_w, const float* __restrict__ sa_out_w,
    const float* __restrict__ ca_in_w, const float* __restrict__ ca_out_w,
    ushort* __restrict__ dst)
{
    int y = blockIdx.y, l = y / 6, m = y % 6;
    const float* W;
    switch (m) {
        case 0: W = sa_in_w  + (size_t)l * 3 * kD * kD + (size_t)2 * kD * kD; break;
        case 1: W = sa_out_w + (size_t)l * kD * kD; break;
        case 2: W = ca_in_w  + (size_t)l * 3 * kD * kD; break;
        case 3: W = ca_in_w  + (size_t)l * 3 * kD * kD + (size_t)kD * kD; break;
        case 4: W = ca_in_w  + (size_t)l * 3 * kD * kD + (size_t)2 * kD * kD; break;
        default:W = ca_out_w + (size_t)l * kD * kD; break;
    }
    int tid  = blockIdx.x * 256 + threadIdx.x;   // 0..32767
    int lane = tid & 63;
    int tile = tid >> 6;                          // kc*32+ct
    int n  = (tile & 31) * 16 + (lane & 15);
    int kb = (tile >> 5) * 32 + (lane >> 4) * 8;
    const float* src = W + (size_t)n * 512 + kb;
    ushort v[8];
    #pragma unroll
    for (int j = 0; j < 8; ++j) v[j] = f2bf(src[j]);
    uint4 u;
    u.x = (unsigned)v[0] | ((unsigned)v[1] << 16);
    u.y = (unsigned)v[2] | ((unsigned)v[3] << 16);
    u.z = (unsigned)v[4] | ((unsigned)v[5] << 16);
    u.w = (unsigned)v[6] | ((unsigned)v[7] << 16);
    *(uint4*)(dst + (size_t)y * 262144 + (size_t)tid * 8) = u;
}

// Generic pack: W is (N x K) row-major; blockIdx.y selects matrix.
__global__ __launch_bounds__(256) void pack_generic_kernel(
    const float* __restrict__ src, size_t srcStride,
    ushort* __restrict__ dst, size_t dstStride, int N, int K)
{
    int tid  = blockIdx.x * 256 + threadIdx.x;
    int NT = N >> 4;
    int lane = tid & 63;
    int tile = tid >> 6;
    int ct = tile % NT, kc = tile / NT;
    int n  = ct * 16 + (lane & 15);
    int kb = kc * 32 + (lane >> 4) * 8;
    const float* W = src + blockIdx.y * srcStride + (size_t)n * K + kb;
    ushort v[8];
    #pragma unroll
    for (int j = 0; j < 8; ++j) v[j] = f2bf(W[j]);
    uint4 u;
    u.x = (unsigned)v[0] | ((unsigned)v[1] << 16);
    u.y = (unsigned)v[2] | ((unsigned)v[3] << 16);
    u.z = (unsigned)v[4] | ((unsigned)v[5] << 16);
    u.w = (unsigned)v[6] | ((unsigned)v[7] << 16);
    *(uint4*)(dst + blockIdx.y * dstStride + (size_t)tid * 8) = u;
}

// ---------------------------------------------------------------------------
// MFMA node_h — merged 3-segment dispatch, 32 rows/block, 2 blocks/CU.
// nids preloaded to LDS (removes dependent index load from gather chain).
// ---------------------------------------------------------------------------
__global__ __launch_bounds__(512, 4) void node_h_mfma(
    const int* __restrict__ nid0a, const float* __restrict__ content0a,
    ushort* __restrict__ outB0, int n0,
    const int* __restrict__ nid1a, const float* __restrict__ content1a,
    ushort* __restrict__ outB1, int n1,
    const int* __restrict__ nid2a, const float* __restrict__ content2a,
    ushort* __restrict__ outB2, float* __restrict__ outF2, int n2,
    const float* __restrict__ node_emb_w,
    const ushort* __restrict__ Bp,
    const float* __restrict__ ee_b, const float* __restrict__ proj_b,
    const float* __restrict__ proj_g, const float* __restrict__ proj_beta)
{
    __shared__ __align__(16) ushort As[kRowsN * kLdA];        // 37376 B
    __shared__ int nids[kRowsN];
    __shared__ float redS[8][kRowsN], redQ[8][kRowsN];
    __shared__ float meanv[kRowsN], rstdv[kRowsN], rowinv[kRowsN];

    const int t    = threadIdx.x;
    const int lane = t & 63;
    const int wv   = t >> 6;
    const int quad = lane >> 4;
    const int l15  = lane & 15;

    const int g0 = (n0 + kRowsN - 1) / kRowsN;
    const int g1 = (n1 + kRowsN - 1) / kRowsN;
    int bx = blockIdx.x;
    const int* nid; const float* content; ushort* outB; float* outF = nullptr;
    int ldh, n;
    if (bx < g0)           { nid = nid0a; content = content0a; outB = outB0; ldh = 512;  n = n0; }
    else if (bx < g0 + g1) { bx -= g0; nid = nid1a; content = content1a; outB = outB1; ldh = 1024; n = n1; }
    else                   { bx -= g0 + g1; nid = nid2a; content = content2a; outB = outB2; outF = outF2; ldh = 512; n = n2; }
    const int row0 = bx * kRowsN;

    if (t < kRowsN) {
        int row = row0 + t; if (row >= n) row = n - 1;
        nids[t] = nid[row] + 1;
    }
    __syncthreads();

    // stage 32 rows x 576 cols (emb 256 | content 300 | pad) fp32->bf16
    // 32*144 = 4608 float4 slots = 9 * 512 exact
    #pragma unroll
    for (int it = 0; it < 9; ++it) {
        int flat = it * 512 + t;
        int r  = flat / 144;
        int k4 = flat - r * 144;
        float4 f = make_float4(0.f, 0.f, 0.f, 0.f);
        if (k4 < 64)
            f = *(const float4*)(node_emb_w + (size_t)nids[r] * 256 + k4 * 4);
        else if (k4 < 139) {
            int row = row0 + r; if (row >= n) row = n - 1;
            f = *(const float4*)(content + (size_t)row * 300 + (k4 - 64) * 4);
        }
        ushort4 o = make_ushort4(f2bf(f.x), f2bf(f.y), f2bf(f.z), f2bf(f.w));
        *(ushort4*)(As + (size_t)r * kLdA + k4 * 4) = o;
    }
    __syncthreads();

    floatx4 acc[2][4] = {};
    const short8* BpV = (const short8*)Bp;

    // ---- phase 1: content @ proj_w^T  (kc 8..17) ----
    #pragma unroll
    for (int kc = 8; kc < 18; ++kc) {
        const short8* bp = BpV + (size_t)(kc * 32 + wv * 4) * 64 + lane;
        short8 b0 = bp[0], b1 = bp[64], b2 = bp[128], b3 = bp[192];
        short8 a[2];
        #pragma unroll
        for (int rt = 0; rt < 2; ++rt)
            a[rt] = *(const short8*)(As + (size_t)(rt * 16 + l15) * kLdA + kc * 32 + quad * 8);
        #pragma unroll
        for (int rt = 0; rt < 2; ++rt) {
            acc[rt][0] = __builtin_amdgcn_mfma_f32_16x16x32_bf16(a[rt], b0, acc[rt][0], 0, 0, 0);
            acc[rt][1] = __builtin_amdgcn_mfma_f32_16x16x32_bf16(a[rt], b1, acc[rt][1], 0, 0, 0);
            acc[rt][2] = __builtin_amdgcn_mfma_f32_16x16x32_bf16(a[rt], b2, acc[rt][2], 0, 0, 0);
            acc[rt][3] = __builtin_amdgcn_mfma_f32_16x16x32_bf16(a[rt], b3, acc[rt][3], 0, 0, 0);
        }
    }

    const int colbase = wv * 64 + l15;
    float pb[4], pg[4], pbt[4], eb[4];
    #pragma unroll
    for (int ct = 0; ct < 4; ++ct) {
        int c = colbase + ct * 16;
        pb[ct]  = proj_b[c];
        pg[ct]  = proj_g[c];
        pbt[ct] = proj_beta[c];
        eb[ct]  = ee_b[c];
    }

    // leaky + partial LN stats
    float s8[8], q8[8];
    #pragma unroll
    for (int rt = 0; rt < 2; ++rt) {
        #pragma unroll
        for (int i = 0; i < 4; ++i) {
            float s = 0.f, q = 0.f;
            #pragma unroll
            for (int ct = 0; ct < 4; ++ct) {
                float c = acc[rt][ct][i] + pb[ct];
                c = (c >= 0.f) ? c : 0.1f * c;
                acc[rt][ct][i] = c;
                s += c; q = fmaf(c, c, q);
            }
            s8[rt * 4 + i] = s; q8[rt * 4 + i] = q;
        }
    }
    #pragma unroll
    for (int idx = 0; idx < 8; ++idx) {
        #pragma unroll
        for (int m = 1; m < 16; m <<= 1) {
            s8[idx] += __shfl_xor(s8[idx], m);
            q8[idx] += __shfl_xor(q8[idx], m);
        }
    }
    if (l15 == 0) {
        #pragma unroll
        for (int rt = 0; rt < 2; ++rt)
            #pragma unroll
            for (int i = 0; i < 4; ++i) {
                int rl = rt * 16 + quad * 4 + i;
                redS[wv][rl] = s8[rt * 4 + i];
                redQ[wv][rl] = q8[rt * 4 + i];
            }
    }
    __syncthreads();
    if (t < kRowsN) {
        float s = 0.f, q = 0.f;
        #pragma unroll
        for (int w = 0; w < 8; ++w) { s += redS[w][t]; q += redQ[w][t]; }
        float m   = s * (1.f / 512.f);
        float var = q * (1.f / 512.f) - m * m;
        meanv[t] = m;
        rstdv[t] = rsqrtf(var + 1e-5f);
    }
    __syncthreads();

    // acc := normalized-content + ee_b  (emb MFMAs accumulate on top)
    #pragma unroll
    for (int rt = 0; rt < 2; ++rt) {
        #pragma unroll
        for (int i = 0; i < 4; ++i) {
            int rl = rt * 16 + quad * 4 + i;
            float m = meanv[rl], rs = rstdv[rl];
            #pragma unroll
            for (int ct = 0; ct < 4; ++ct)
                acc[rt][ct][i] = (acc[rt][ct][i] - m) * rs * pg[ct] + pbt[ct] + eb[ct];
        }
    }

    // ---- phase 2: emb @ ee_w^T  (kc 0..7) ----
    #pragma unroll
    for (int kc = 0; kc < 8; ++kc) {
        const short8* bp = BpV + (size_t)(kc * 32 + wv * 4) * 64 + lane;
        short8 b0 = bp[0], b1 = bp[64], b2 = bp[128], b3 = bp[192];
        short8 a[2];
        #pragma unroll
        for (int rt = 0; rt < 2; ++rt)
            a[rt] = *(const short8*)(As + (size_t)(rt * 16 + l15) * kLdA + kc * 32 + quad * 8);
        #pragma unroll
        for (int rt = 0; rt < 2; ++rt) {
            acc[rt][0] = __builtin_amdgcn_mfma_f32_16x16x32_bf16(a[rt], b0, acc[rt][0], 0, 0, 0);
            acc[rt][1] = __builtin_amdgcn_mfma_f32_16x16x32_bf16(a[rt], b1, acc[rt][1], 0, 0, 0);
            acc[rt][2] = __builtin_amdgcn_mfma_f32_16x16x32_bf16(a[rt], b2, acc[rt][2], 0, 0, 0);
            acc[rt][3] = __builtin_amdgcn_mfma_f32_16x16x32_bf16(a[rt], b3, acc[rt][3], 0, 0, 0);
        }
    }

    // ---- row norm ----
    #pragma unroll
    for (int rt = 0; rt < 2; ++rt) {
        #pragma unroll
        for (int i = 0; i < 4; ++i) {
            float psq = 0.f;
            #pragma unroll
            for (int ct = 0; ct < 4; ++ct)
                psq = fmaf(acc[rt][ct][i], acc[rt][ct][i], psq);
            q8[rt * 4 + i] = psq;
        }
    }
    #pragma unroll
    for (int idx = 0; idx < 8; ++idx)
        #pragma unroll
        for (int m = 1; m < 16; m <<= 1)
            q8[idx] += __shfl_xor(q8[idx], m);
    if (l15 == 0) {
        #pragma unroll
        for (int rt = 0; rt < 2; ++rt)
            #pragma unroll
            for (int i = 0; i < 4; ++i)
                redS[wv][rt * 16 + quad * 4 + i] = q8[rt * 4 + i];
    }
    __syncthreads();
    if (t < kRowsN) {
        float s = 0.f;
        #pragma unroll
        for (int w = 0; w < 8; ++w) s += redS[w][t];
        rowinv[t] = 1.f / fmaxf(sqrtf(s), 1e-5f);
    }
    __syncthreads();

    #pragma unroll
    for (int rt = 0; rt < 2; ++rt) {
        #pragma unroll
        for (int i = 0; i < 4; ++i) {
            int rl = rt * 16 + quad * 4 + i;
            int grow = row0 + rl;
            if (grow < n) {
                float inv = rowinv[rl];
                ushort* dB = outB + (size_t)grow * ldh + colbase;
                #pragma unroll
                for (int ct = 0; ct < 4; ++ct) {
                    float v = acc[rt][ct][i] * inv;
                    dB[ct * 16] = f2bf(v);
                    if (outF) outF[(size_t)grow * ldh + colbase + ct * 16] = v;
                }
            }
        }
    }
}

// ---------------------------------------------------------------------------
// MFMA GEMM, bf16 A-operand: C = A(MxK,bf16) @ W^T + bias, fused epilogue.
// 48 rows x 512 cols per block. EPI: 0=plain->bf16  1=gelu->bf16
// 2=residual(fp32)+LayerNorm -> fp32 Cf AND bf16 Cb (N==512, nb==0)
// ---------------------------------------------------------------------------
__device__ inline float gelu_exact(float x) {
    return 0.5f * x * (1.f + erff(x * 0.70710678118654752f));
}

template<int EPI>
__global__ __launch_bounds__(512, 2) void gemm_mfma(
    const ushort* __restrict__ A, int lda,
    const ushort* __restrict__ Bp, const float* __restrict__ bias,
    ushort* __restrict__ Cb, float* __restrict__ Cf, int ldc,
    const float* __restrict__ resid,
    const float* __restrict__ lng, const float* __restrict__ lnb,
    int M, int K, int N)
{
    __shared__ __align__(16) ushort As[kRows * kLdG];      // 49920 B
    __shared__ float redS[8][kRows], redQ[8][kRows];
    __shared__ float meanv[kRows], rstdv[kRows];

    const int t    = threadIdx.x;
    const int lane = t & 63;
    const int wv   = t >> 6;
    const int quad = lane >> 4;
    const int l15  = lane & 15;
    const int row0 = blockIdx.x * kRows;
    const int nb   = blockIdx.y;
    const int NT   = N >> 4;

    floatx4 acc[3][4] = {};
    const short8* BpV = (const short8*)Bp;

    for (int k0 = 0; k0 < K; k0 += 512) {
        // stage A chunk (48 x 512) bf16 direct: 3072 x 16B slots = 6*512
        #pragma unroll
        for (int it = 0; it < 6; ++it) {
            int flat = it * 512 + t;
            int r  = flat >> 6;          // 64 slots per row
            int k8 = flat & 63;
            int row = row0 + r; if (row >= M) row = M - 1;
            short8 v = *(const short8*)(A + (size_t)row * lda + k0 + k8 * 8);
            *(short8*)(As + (size_t)r * kLdG + k8 * 8) = v;
        }
        __syncthreads();
        const int g0 = k0 >> 5;
        #pragma unroll
        for (int kc = 0; kc < 16; ++kc) {
            const short8* bp = BpV + ((size_t)(g0 + kc) * NT + nb * 32 + wv * 4) * 64 + lane;
            short8 b0 = bp[0], b1 = bp[64], b2 = bp[128], b3 = bp[192];
            short8 a[3];
            #pragma unroll
            for (int rt = 0; rt < 3; ++rt)
                a[rt] = *(const short8*)(As + (size_t)(rt * 16 + l15) * kLdG + kc * 32 + quad * 8);
            #pragma unroll
            for (int rt = 0; rt < 3; ++rt) {
                acc[rt][0] = __builtin_amdgcn_mfma_f32_16x16x32_bf16(a[rt], b0, acc[rt][0], 0, 0, 0);
                acc[rt][1] = __builtin_amdgcn_mfma_f32_16x16x32_bf16(a[rt], b1, acc[rt][1], 0, 0, 0);
                acc[rt][2] = __builtin_amdgcn_mfma_f32_16x16x32_bf16(a[rt], b2, acc[rt][2], 0, 0, 0);
                acc[rt][3] = __builtin_amdgcn_mfma_f32_16x16x32_bf16(a[rt], b3, acc[rt][3], 0, 0, 0);
            }
        }
        __syncthreads();
    }

    const int colloc = wv * 64 + l15;           // 0..511 within col-block
    float b[4];
    #pragma unroll
    for (int ct = 0; ct < 4; ++ct) b[ct] = bias[nb * 512 + colloc + ct * 16];

    if constexpr (EPI == 0 || EPI == 1) {
        #pragma unroll
        for (int rt = 0; rt < 3; ++rt) {
            #pragma unroll
            for (int i = 0; i < 4; ++i) {
                int row = row0 + rt * 16 + quad * 4 + i;
                if (row < M) {
                    ushort* dst = Cb + (size_t)row * ldc + nb * 512 + colloc;
                    #pragma unroll
                    for (int ct = 0; ct < 4; ++ct) {
                        float v = acc[rt][ct][i] + b[ct];
                        if (EPI == 1) v = gelu_exact(v);
                        dst[ct * 16] = f2bf(v);
                    }
                }
            }
        }
    } else {
        float lg[4], lb[4];
        #pragma unroll
        for (int ct = 0; ct < 4; ++ct) {
            lg[ct] = lng[colloc + ct * 16];
            lb[ct] = lnb[colloc + ct * 16];
        }
        float s12[12], q12[12];
        #pragma unroll
        for (int rt = 0; rt < 3; ++rt) {
            #pragma unroll
            for (int i = 0; i < 4; ++i) {
                int rl = rt * 16 + quad * 4 + i;
                int row = row0 + rl; if (row >= M) row = M - 1;
                const float* rr = resid + (size_t)row * 512 + colloc;
                float s = 0.f, q = 0.f;
                #pragma unroll
                for (int ct = 0; ct < 4; ++ct) {
                    float h = acc[rt][ct][i] + b[ct] + rr[ct * 16];
                    acc[rt][ct][i] = h;
                    s += h; q = fmaf(h, h, q);
                }
                s12[rt * 4 + i] = s; q12[rt * 4 + i] = q;
            }
        }
        #pragma unroll
        for (int idx = 0; idx < 12; ++idx) {
            #pragma unroll
            for (int m = 1; m < 16; m <<= 1) {
                s12[idx] += __shfl_xor(s12[idx], m);
                q12[idx] += __shfl_xor(q12[idx], m);
            }
        }
        if (l15 == 0) {
            #pragma unroll
            for (int rt = 0; rt < 3; ++rt)
                #pragma unroll
                for (int i = 0; i < 4; ++i) {
                    int rl = rt * 16 + quad * 4 + i;
                    redS[wv][rl] = s12[rt * 4 + i];
                    redQ[wv][rl] = q12[rt * 4 + i];
                }
        }
        __syncthreads();
        if (t < kRows) {
            float s = 0.f, q = 0.f;
            #pragma unroll
            for (int w = 0; w < 8; ++w) { s += redS[w][t]; q += redQ[w][t]; }
            float m   = s * (1.f / 512.f);
            float var = q * (1.f / 512.f) - m * m;
            meanv[t] = m;
            rstdv[t] = rsqrtf(var + 1e-5f);
        }
        __syncthreads();
        #pragma unroll
        for (int rt = 0; rt < 3; ++rt) {
            #pragma unroll
            for (int i = 0; i < 4; ++i) {
                int rl = rt * 16 + quad * 4 + i;
                int row = row0 + rl;
                if (row < M) {
                    float m = meanv[rl], rs = rstdv[rl];
                    float*  dF = Cf + (size_t)row * 512 + colloc;
                    ushort* dB = Cb + (size_t)row * 512 + colloc;
                    #pragma unroll
                    for (int ct = 0; ct < 4; ++ct) {
                        float v = (acc[rt][ct][i] - m) * rs * lg[ct] + lb[ct];
                        dF[ct * 16] = v;
                        dB[ct * 16] = f2bf(v);
                    }
                }
            }
        }
    }
}

// ---------------------------------------------------------------------------
// Merged 3-way GEMM (all K=512, N=512, bf16 A, bf16 C, plain epilogue).
// ---------------------------------------------------------------------------
__global__ __launch_bounds__(512, 2) void gemm3_mfma(
    const ushort* __restrict__ A0, const ushort* __restrict__ B0,
    const float* __restrict__ b0p, ushort* __restrict__ C0, int M0,
    const ushort* __restrict__ A1, const ushort* __restrict__ B1,
    const float* __restrict__ b1p, ushort* __restrict__ C1, int M1,
    const ushort* __restrict__ A2, const ushort* __restrict__ B2,
    const float* __restrict__ b2p, ushort* __restrict__ C2, int M2)
{
    __shared__ __align__(16) ushort As[kRows * kLdG];

    const int t    = threadIdx.x;
    const int lane = t & 63;
    const int wv   = t >> 6;
    const int quad = lane >> 4;
    const int l15  = lane & 15;

    const int g0 = (M0 + kRows - 1) / kRows;
    const int g1 = (M1 + kRows - 1) / kRows;
    int bx = blockIdx.x;
    const ushort* A; const ushort* Bw; const float* bias; ushort* C; int M;
    if (bx < g0)           { A = A0; Bw = B0; bias = b0p; C = C0; M = M0; }
    else if (bx < g0 + g1) { bx -= g0; A = A1; Bw = B1; bias = b1p; C = C1; M = M1; }
    else                   { bx -= g0 + g1; A = A2; Bw = B2; bias = b2p; C = C2; M = M2; }
    const int row0 = bx * kRows;

    floatx4 acc[3][4] = {};
    const short8* BpV = (const short8*)Bw;

    #pragma unroll
    for (int it = 0; it < 6; ++it) {
        int flat = it * 512 + t;
        int r  = flat >> 6;
        int k8 = flat & 63;
        int row = row0 + r; if (row >= M) row = M - 1;
        short8 v = *(const short8*)(A + (size_t)row * 512 + k8 * 8);
        *(short8*)(As + (size_t)r * kLdG + k8 * 8) = v;
    }
    __syncthreads();
    #pragma unroll
    for (int kc = 0; kc < 16; ++kc) {
        const short8* bp = BpV + ((size_t)kc * 32 + wv * 4) * 64 + lane;
        short8 b0 = bp[0], b1 = bp[64], b2 = bp[128], b3 = bp[192];
        short8 a[3];
        #pragma unroll
        for (int rt = 0; rt < 3; ++rt)
            a[rt] = *(const short8*)(As + (size_t)(rt * 16 + l15) * kLdG + kc * 32 + quad * 8);
        #pragma unroll
        for (int rt = 0; rt < 3; ++rt) {
            acc[rt][0] = __builtin_amdgcn_mfma_f32_16x16x32_bf16(a[rt], b0, acc[rt][0], 0, 0, 0);
            acc[rt][1] = __builtin_amdgcn_mfma_f32_16x16x32_bf16(a[rt], b1, acc[rt][1], 0, 0, 0);
            acc[rt][2] = __builtin_amdgcn_mfma_f32_16x16x32_bf16(a[rt], b2, acc[rt][2], 0, 0, 0);
            acc[rt][3] = __builtin_amdgcn_mfma_f32_16x16x32_bf16(a[rt], b3, acc[rt][3], 0, 0, 0);
        }
    }

    const int colloc = wv * 64 + l15;
    float b[4];
    #pragma unroll
    for (int ct = 0; ct < 4; ++ct) b[ct] = bias[colloc + ct * 16];
    #pragma unroll
    for (int rt = 0; rt < 3; ++rt) {
        #pragma unroll
        for (int i = 0; i < 4; ++i) {
            int row = row0 + rt * 16 + quad * 4 + i;
            if (row < M) {
                ushort* dst = C + (size_t)row * 512 + colloc;
                #pragma unroll
                for (int ct = 0; ct < 4; ++ct)
                    dst[ct * 16] = f2bf(acc[rt][ct][i] + b[ct]);
            }
        }
    }
}

// ---------------------------------------------------------------------------
__device__ inline float block_sum256(float v, float* red4) {
    #pragma unroll
    for (int off = 32; off > 0; off >>= 1) v += __shfl_down(v, off);
    if ((threadIdx.x & 63) == 0) red4[threadIdx.x >> 6] = v;
    __syncthreads();
    return red4[0] + red4[1] + red4[2] + red4[3];
}

__global__ __launch_bounds__(256) void agg_norm1_kernel(
    const ushort* __restrict__ h0, const int* __restrict__ esrc,
    ushort* __restrict__ h1cat)
{
    __shared__ int idx[kDeg];
    __shared__ float red4[4];
    int i = blockIdx.x, t = threadIdx.x;
    if (t < kDeg) idx[t] = esrc[i * kDeg + t];
    __syncthreads();
    float s0 = 0.f, s1 = 0.f;
    for (int e = 0; e < kDeg; ++e) {
        const ushort* hr = h0 + (size_t)idx[e] * 512;
        s0 += bf2f(hr[t]); s1 += bf2f(hr[t + 256]);
    }
    s0 *= 0.1f; s1 *= 0.1f;
    size_t base = (size_t)i * 1024;
    float o0 = bf2f(h1cat[base + 512 + t]);
    float o1 = bf2f(h1cat[base + 768 + t]);
    float tot = block_sum256(s0 * s0 + s1 * s1 + o0 * o0 + o1 * o1, red4);
    float inv = 1.f / fmaxf(sqrtf(tot), 1e-5f);
    h1cat[base + t]       = f2bf(s0 * inv);
    h1cat[base + 256 + t] = f2bf(s1 * inv);
    h1cat[base + 512 + t] = f2bf(o0 * inv);
    h1cat[base + 768 + t] = f2bf(o1 * inv);
}

__global__ __launch_bounds__(256) void agg2_kernel(
    const ushort* __restrict__ h1cat, const int* __restrict__ esrc,
    ushort* __restrict__ m2)
{
    __shared__ int idx[kDeg];
    int i = blockIdx.x, t = threadIdx.x;
    if (t < kDeg) idx[t] = esrc[i * kDeg + t];
    __syncthreads();
    float s0 = 0.f, s1 = 0.f, s2 = 0.f, s3 = 0.f;
    for (int e = 0; e < kDeg; ++e) {
        const ushort* hr = h1cat + (size_t)idx[e] * 1024;
        s0 += bf2f(hr[t]);       s1 += bf2f(hr[t + 256]);
        s2 += bf2f(hr[t + 512]); s3 += bf2f(hr[t + 768]);
    }
    size_t base = (size_t)i * 1024;
    m2[base + t]       = f2bf(s0 * 0.1f);
    m2[base + 256 + t] = f2bf(s1 * 0.1f);
    m2[base + 512 + t] = f2bf(s2 * 0.1f);
    m2[base + 768 + t] = f2bf(s3 * 0.1f);
}

// Kb/Vb rows: 2i = memory slot 0, 2i+1 = slot 1 (m2 viewed as (2*N2, 512)).
__global__ __launch_bounds__(256) void attn_combine_kernel(
    const ushort* __restrict__ Q,
    const ushort* __restrict__ Kb, const ushort* __restrict__ Vb,
    ushort* __restrict__ O)
{
    __shared__ float red[4][4];
    __shared__ float a[4];
    int i = blockIdx.x, t = threadIdx.x;
    size_t base  = (size_t)i * 512;
    size_t base0 = (size_t)(2 * i) * 512;
    size_t base1 = base0 + 512;
    float q0 = bf2f(Q[base + t]), q1 = bf2f(Q[base + t + 256]);
    float p00 = q0 * bf2f(Kb[base0 + t]);
    float p01 = q0 * bf2f(Kb[base1 + t]);
    float p10 = q1 * bf2f(Kb[base0 + t + 256]);
    float p11 = q1 * bf2f(Kb[base1 + t + 256]);
    #pragma unroll
    for (int off = 32; off > 0; off >>= 1) {
        p00 += __shfl_down(p00, off);
        p01 += __shfl_down(p01, off);
        p10 += __shfl_down(p10, off);
        p11 += __shfl_down(p11, off);
    }
    int w = t >> 6;
    if ((t & 63) == 0) { red[w][0] = p00; red[w][1] = p01; red[w][2] = p10; red[w][3] = p11; }
    __syncthreads();
    if (t == 0) {
        float s00 = (red[0][0] + red[1][0] + red[2][0] + red[3][0]) * 0.0625f;
        float s01 = (red[0][1] + red[1][1] + red[2][1] + red[3][1]) * 0.0625f;
        float s10 = (red[0][2] + red[1][2] + red[2][2] + red[3][2]) * 0.0625f;
        float s11 = (red[0][3] + red[1][3] + red[2][3] + red[3][3]) * 0.0625f;
        float m0 = fmaxf(s00, s01);
        float e0 = expf(s00 - m0), e1 = expf(s01 - m0);
        float d0 = e0 + e1;
        a[0] = e0 / d0; a[1] = e1 / d0;
        float m1 = fmaxf(s10, s11);
        float f0 = expf(s10 - m1), f1 = expf(s11 - m1);
        float d1 = f0 + f1;
        a[2] = f0 / d1; a[3] = f1 / d1;
    }
    __syncthreads();
    O[base + t]       = f2bf(a[0] * bf2f(Vb[base0 + t])       + a[1] * bf2f(Vb[base1 + t]));
    O[base + t + 256] = f2bf(a[2] * bf2f(Vb[base0 + t + 256]) + a[3] * bf2f(Vb[base1 + t + 256]));
}

__global__ __launch_bounds__(256) void final_norm_kernel(
    const float* __restrict__ tgt, float* __restrict__ out)
{
    __shared__ float red4[4];
    int i = blockIdx.x, t = threadIdx.x;
    size_t base = (size_t)i * 512;
    float v0 = tgt[base + t], v1 = tgt[base + t + 256];
    float tot = block_sum256(v0 * v0 + v1 * v1, red4);
    float inv = 1.f / fmaxf(sqrtf(tot), 1e-5f);
    out[base + t]       = v0 * inv;
    out[base + t + 256] = v1 * inv;
}

// ---------------------------------------------------------------------------
extern "C" void kernel_launch(void* const* d_in, const int* in_sizes, int n_in,
                              void* d_out, int out_size, void* d_ws, size_t ws_size,
                              hipStream_t stream)
{
    (void)in_sizes; (void)n_in; (void)out_size; (void)ws_size;
    const int*   nid0       = (const int*)d_in[0];
    const int*   nid1       = (const int*)d_in[1];
    const int*   nid2       = (const int*)d_in[2];
    const int*   esrc0      = (const int*)d_in[3];
    const int*   esrc1      = (const int*)d_in[5];
    const float* content0   = (const float*)d_in[7];
    const float* content1   = (const float*)d_in[8];
    const float* content2   = (const float*)d_in[9];
    const float* node_emb_w = (const float*)d_in[10];
    const float* ee_w       = (const float*)d_in[11];
    const float* ee_b       = (const float*)d_in[12];
    const float* proj_w     = (const float*)d_in[13];
    const float* proj_b     = (const float*)d_in[14];
    const float* proj_g     = (const float*)d_in[15];
    const float* proj_beta  = (const float*)d_in[16];
    const float* sa_in_w    = (const float*)d_in[17];
    const float* sa_in_b    = (const float*)d_in[18];
    const float* sa_out_w   = (const float*)d_in[19];
    const float* sa_out_b   = (const float*)d_in[20];
    const float* ca_in_w    = (const float*)d_in[21];
    const float* ca_in_b    = (const float*)d_in[22];
    const float* ca_out_w   = (const float*)d_in[23];
    const float* ca_out_b   = (const float*)d_in[24];
    const float* lin1_w     = (const float*)d_in[25];
    const float* lin1_b     = (const float*)d_in[26];
    const float* lin2_w     = (const float*)d_in[27];
    const float* lin2_b     = (const float*)d_in[28];
    const float* n1_g       = (const float*)d_in[29];
    const float* n1_b       = (const float*)d_in[30];
    const float* n2_g       = (const float*)d_in[31];
    const float* n2_b       = (const float*)d_in[32];
    const float* n3_g       = (const float*)d_in[33];
    const float* n3_b       = (const float*)d_in[34];

    float* ws = (float*)d_ws;
    size_t off = 0;
    ushort* h0b    = (ushort*)(ws + off); off += (size_t)kN0 * 512 / 2;
    ushort* h1catb = (ushort*)(ws + off); off += (size_t)kN1 * 1024 / 2;
    ushort* m2b    = (ushort*)(ws + off); off += (size_t)kN2 * 1024 / 2;
    float*  tgt    = ws + off;            off += (size_t)kN2 * 512;
    ushort* tgtb   = (ushort*)(ws + off); off += (size_t)kN2 * 512 / 2;
    ushort* Qbb    = (ushort*)(ws + off); off += (size_t)kN2 * 512 / 2;
    ushort* Kbb    = (ushort*)(ws + off); off += (size_t)2 * kN2 * 512 / 2;
    ushort* Vbb    = (ushort*)(ws + off); off += (size_t)2 * kN2 * 512 / 2;
    ushort* Obb    = (ushort*)(ws + off); off += (size_t)kN2 * 512 / 2;
    ushort* ffhb   = (ushort*)(ws + off); off += (size_t)kN2 * 2048 / 2;
    ushort* BpNode = (ushort*)(ws + off); off += 147456;           // 576*64*8 bf16
    ushort* Pw512  = (ushort*)(ws + off); off += 12 * 262144 / 2;  // 12 x 512x512
    ushort* Pl1    = (ushort*)(ws + off); off += 2 * 1048576 / 2;  // 2 x 2048x512
    ushort* Pl2    = (ushort*)(ws + off); off += 2 * 1048576 / 2;  // 2 x 512x2048

    dim3 blk(256);

    // ---- weight packing (4 launches) ----
    pack_node_w_kernel<<<dim3(144), blk, 0, stream>>>(ee_w, proj_w, BpNode);
    pack512_many_kernel<<<dim3(128, 12), blk, 0, stream>>>(
        sa_in_w, sa_out_w, ca_in_w, ca_out_w, Pw512);
    pack_generic_kernel<<<dim3(512, 2), blk, 0, stream>>>(
        lin1_w, (size_t)kFF * kD, Pl1, 1048576, kFF, kD);
    pack_generic_kernel<<<dim3(512, 2), blk, 0, stream>>>(
        lin2_w, (size_t)kD * kFF, Pl2, 1048576, kD, kFF);

    // ---- node_h (merged 3-segment dispatch, 2 blocks/CU) ----
    {
        int g0 = (kN0 + kRowsN - 1) / kRowsN;   // 3125
        int g1 = (kN1 + kRowsN - 1) / kRowsN;   // 625
        int g2 = (kN2 + kRowsN - 1) / kRowsN;   // 125
        node_h_mfma<<<dim3(g0 + g1 + g2), dim3(512), 0, stream>>>(
            nid0, content0, h0b, kN0,
            nid1, content1, h1catb + 512, kN1,
            nid2, content2, tgtb, tgt, kN2,
            node_emb_w, BpNode, ee_b, proj_b, proj_g, proj_beta);
    }

    agg_norm1_kernel<<<dim3(kN1), blk, 0, stream>>>(h0b, esrc0, h1catb);
    agg2_kernel<<<dim3(kN2), blk, 0, stream>>>(h1catb, esrc1, m2b);

    const int M   = kN2;
    const int gM  = (M + kRows - 1) / kRows;       // 84
    const int gM2 = (2 * M + kRows - 1) / kRows;   // 167
    dim3 blk512(512);
    for (int l = 0; l < 2; ++l) {
        const ushort* sa_v_p   = Pw512 + (size_t)(l * 6 + 0) * 262144;
        const ushort* sa_out_p = Pw512 + (size_t)(l * 6 + 1) * 262144;
        const ushort* ca_q_p   = Pw512 + (size_t)(l * 6 + 2) * 262144;
        const ushort* ca_k_p   = Pw512 + (size_t)(l * 6 + 3) * 262144;
        const ushort* ca_v_p   = Pw512 + (size_t)(l * 6 + 4) * 262144;
        const ushort* ca_out_p = Pw512 + (size_t)(l * 6 + 5) * 262144;
        const ushort* l1_p     = Pl1 + (size_t)l * 1048576;
        const ushort* l2_p     = Pl2 + (size_t)l * 1048576;
        const float* sa_b = sa_in_b + (size_t)l * 3 * kD;
        const float* saob = sa_out_b + (size_t)l * kD;
        const float* ca_b = ca_in_b + (size_t)l * 3 * kD;
        const float* caob = ca_out_b + (size_t)l * kD;
        const float* l1b = lin1_b + (size_t)l * kFF;
        const float* l2b = lin2_b + (size_t)l * kD;

        // merged: sa_v (tgtb), ca_k (m2b), ca_v (m2b) — all independent here
        gemm3_mfma<<<dim3(gM + gM2 + gM2), blk512, 0, stream>>>(
            tgtb, sa_v_p, sa_b + 2 * kD, Qbb, M,
            m2b,  ca_k_p, ca_b + kD,     Kbb, 2 * M,
            m2b,  ca_v_p, ca_b + 2 * kD, Vbb, 2 * M);

        // self-attention (seq len 1 => o = v-projection)
        gemm_mfma<2><<<dim3(gM, 1), blk512, 0, stream>>>(
            Qbb, 512, sa_out_p, saob, tgtb, tgt, 512,
            tgt, n1_g + l * kD, n1_b + l * kD, M, 512, 512);

        // cross-attention
        gemm_mfma<0><<<dim3(gM, 1), blk512, 0, stream>>>(
            tgtb, 512, ca_q_p, ca_b, Qbb, nullptr, 512,
            nullptr, nullptr, nullptr, M, 512, 512);
        attn_combine_kernel<<<dim3(M), blk, 0, stream>>>(Qbb, Kbb, Vbb, Obb);
        gemm_mfma<2><<<dim3(gM, 1), blk512, 0, stream>>>(
            Obb, 512, ca_out_p, caob, tgtb, tgt, 512,
            tgt, n2_g + l * kD, n2_b + l * kD, M, 512, 512);

        // feed-forward
        gemm_mfma<1><<<dim3(gM, 4), blk512, 0, stream>>>(
            tgtb, 512, l1_p, l1b, ffhb, nullptr, 2048,
            nullptr, nullptr, nullptr, M, 512, 2048);
        gemm_mfma<2><<<dim3(gM, 1), blk512, 0, stream>>>(
            ffhb, 2048, l2_p, l2b, tgtb, tgt, 512,
            tgt, n3_g + l * kD, n3_b + l * kD, M, 2048, 512);
    }

    final_norm_kernel<<<dim3(kN2), blk, 0, stream>>>(tgt, (float*)d_out);
}

// Round 11
// 939.611 us; speedup vs baseline: 1.0976x; 1.0302x over previous
//
#include <hip/hip_runtime.h>
#include <math.h>

static constexpr int kN0  = 100000;
static constexpr int kN1  = 20000;
static constexpr int kN2  = 4000;
static constexpr int kDeg = 10;
static constexpr int kD   = 512;
static constexpr int kFF  = 2048;
static constexpr int kRows  = 48;  // rows per MFMA block (gemm)
static constexpr int kRowsN = 32;  // rows per MFMA block (node_h) -> 2 blocks/CU (empirical optimum)
static constexpr int kLdA  = 584;  // node_h LDS row stride (bf16 elems, +8 pad)
static constexpr int kLdG  = 520;  // gemm LDS row stride for 512-k chunk (+8 pad)

using short8  = __attribute__((ext_vector_type(8))) short;
using floatx4 = __attribute__((ext_vector_type(4))) float;

__device__ inline unsigned short f2bf(float f) {
    union { float f; unsigned u; } v; v.f = f;
    unsigned r = v.u + 0x7FFFu + ((v.u >> 16) & 1u);  // RNE
    return (unsigned short)(r >> 16);
}
__device__ inline float bf2f(ushort u) {
    union { unsigned v; float f; } x; x.v = (unsigned)u << 16; return x.f;
}

// ---------------------------------------------------------------------------
// Pack node_h weights (ee_w || proj_w, K padded to 576) into b-frag order.
// ---------------------------------------------------------------------------
__global__ __launch_bounds__(256) void pack_node_w_kernel(
    const float* __restrict__ ee_w, const float* __restrict__ proj_w,
    ushort* __restrict__ Bp)
{
    int tid  = blockIdx.x * 256 + threadIdx.x;   // 0 .. 36863
    int lane = tid & 63;
    int tile = tid >> 6;                          // kc*32 + ct
    int n     = (tile & 31) * 16 + (lane & 15);
    int kbase = (tile >> 5) * 32 + (lane >> 4) * 8;
    ushort v[8];
    #pragma unroll
    for (int j = 0; j < 8; ++j) {
        int k = kbase + j;
        float f = 0.f;
        if (k < 256)      f = ee_w[(size_t)n * 256 + k];
        else if (k < 556) f = proj_w[(size_t)n * 300 + (k - 256)];
        v[j] = f2bf(f);
    }
    uint4 u;
    u.x = (unsigned)v[0] | ((unsigned)v[1] << 16);
    u.y = (unsigned)v[2] | ((unsigned)v[3] << 16);
    u.z = (unsigned)v[4] | ((unsigned)v[5] << 16);
    u.w = (unsigned)v[6] | ((unsigned)v[7] << 16);
    *(uint4*)(Bp + (size_t)tid * 8) = u;
}

// ---------------------------------------------------------------------------
// Pack the 12 (512x512) attention weight matrices into b-frag order.
// ---------------------------------------------------------------------------
__global__ __launch_bounds__(256) void pack512_many_kernel(
    const float* __restrict__ sa_in_w, const float* __restrict__ sa_out_w,
    const float* __restrict__ ca_in_w, const float* __restrict__ ca_out_w,
    ushort* __restrict__ dst)
{
    int y = blockIdx.y, l = y / 6, m = y % 6;
    const float* W;
    switch (m) {
        case 0: W = sa_in_w  + (size_t)l * 3 * kD * kD + (size_t)2 * kD * kD; break;
        case 1: W = sa_out_w + (size_t)l * kD * kD; break;
        case 2: W = ca_in_w  + (size_t)l * 3 * kD * kD; break;
        case 3: W = ca_in_w  + (size_t)l * 3 * kD * kD + (size_t)kD * kD; break;
        case 4: W = ca_in_w  + (size_t)l * 3 * kD * kD + (size_t)2 * kD * kD; break;
        default:W = ca_out_w + (size_t)l * kD * kD; break;
    }
    int tid  = blockIdx.x * 256 + threadIdx.x;   // 0..32767
    int lane = tid & 63;
    int tile = tid >> 6;                          // kc*32+ct
    int n  = (tile & 31) * 16 + (lane & 15);
    int kb = (tile >> 5) * 32 + (lane >> 4) * 8;
    const float* src = W + (size_t)n * 512 + kb;
    ushort v[8];
    #pragma unroll
    for (int j = 0; j < 8; ++j) v[j] = f2bf(src[j]);
    uint4 u;
    u.x = (unsigned)v[0] | ((unsigned)v[1] << 16);
    u.y = (unsigned)v[2] | ((unsigned)v[3] << 16);
    u.z = (unsigned)v[4] | ((unsigned)v[5] << 16);
    u.w = (unsigned)v[6] | ((unsigned)v[7] << 16);
    *(uint4*)(dst + (size_t)y * 262144 + (size_t)tid * 8) = u;
}

// Generic pack: W is (N x K) row-major; blockIdx.y selects matrix.
__global__ __launch_bounds__(256) void pack_generic_kernel(
    const float* __restrict__ src, size_t srcStride,
    ushort* __restrict__ dst, size_t dstStride, int N, int K)
{
    int tid  = blockIdx.x * 256 + threadIdx.x;
    int NT = N >> 4;
    int lane = tid & 63;
    int tile = tid >> 6;
    int ct = tile % NT, kc = tile / NT;
    int n  = ct * 16 + (lane & 15);
    int kb = kc * 32 + (lane >> 4) * 8;
    const float* W = src + blockIdx.y * srcStride + (size_t)n * K + kb;
    ushort v[8];
    #pragma unroll
    for (int j = 0; j < 8; ++j) v[j] = f2bf(W[j]);
    uint4 u;
    u.x = (unsigned)v[0] | ((unsigned)v[1] << 16);
    u.y = (unsigned)v[2] | ((unsigned)v[3] << 16);
    u.z = (unsigned)v[4] | ((unsigned)v[5] << 16);
    u.w = (unsigned)v[6] | ((unsigned)v[7] << 16);
    *(uint4*)(dst + blockIdx.y * dstStride + (size_t)tid * 8) = u;
}

// ---------------------------------------------------------------------------
// MFMA node_h — merged 3-segment dispatch, 32 rows/block, 2 blocks/CU.
// nids preloaded to LDS (removes dependent index load from gather chain).
// ---------------------------------------------------------------------------
__global__ __launch_bounds__(512, 4) void node_h_mfma(
    const int* __restrict__ nid0a, const float* __restrict__ content0a,
    ushort* __restrict__ outB0, int n0,
    const int* __restrict__ nid1a, const float* __restrict__ content1a,
    ushort* __restrict__ outB1, int n1,
    const int* __restrict__ nid2a, const float* __restrict__ content2a,
    ushort* __restrict__ outB2, float* __restrict__ outF2, int n2,
    const float* __restrict__ node_emb_w,
    const ushort* __restrict__ Bp,
    const float* __restrict__ ee_b, const float* __restrict__ proj_b,
    const float* __restrict__ proj_g, const float* __restrict__ proj_beta)
{
    __shared__ __align__(16) ushort As[kRowsN * kLdA];        // 37376 B
    __shared__ int nids[kRowsN];
    __shared__ float redS[8][kRowsN], redQ[8][kRowsN];
    __shared__ float meanv[kRowsN], rstdv[kRowsN], rowinv[kRowsN];

    const int t    = threadIdx.x;
    const int lane = t & 63;
    const int wv   = t >> 6;
    const int quad = lane >> 4;
    const int l15  = lane & 15;

    const int g0 = (n0 + kRowsN - 1) / kRowsN;
    const int g1 = (n1 + kRowsN - 1) / kRowsN;
    int bx = blockIdx.x;
    const int* nid; const float* content; ushort* outB; float* outF = nullptr;
    int ldh, n;
    if (bx < g0)           { nid = nid0a; content = content0a; outB = outB0; ldh = 512;  n = n0; }
    else if (bx < g0 + g1) { bx -= g0; nid = nid1a; content = content1a; outB = outB1; ldh = 1024; n = n1; }
    else                   { bx -= g0 + g1; nid = nid2a; content = content2a; outB = outB2; outF = outF2; ldh = 512; n = n2; }
    const int row0 = bx * kRowsN;

    if (t < kRowsN) {
        int row = row0 + t; if (row >= n) row = n - 1;
        nids[t] = nid[row] + 1;
    }
    __syncthreads();

    // stage 32 rows x 576 cols (emb 256 | content 300 | pad) fp32->bf16
    // 32*144 = 4608 float4 slots = 9 * 512 exact
    #pragma unroll
    for (int it = 0; it < 9; ++it) {
        int flat = it * 512 + t;
        int r  = flat / 144;
        int k4 = flat - r * 144;
        float4 f = make_float4(0.f, 0.f, 0.f, 0.f);
        if (k4 < 64)
            f = *(const float4*)(node_emb_w + (size_t)nids[r] * 256 + k4 * 4);
        else if (k4 < 139) {
            int row = row0 + r; if (row >= n) row = n - 1;
            f = *(const float4*)(content + (size_t)row * 300 + (k4 - 64) * 4);
        }
        ushort4 o = make_ushort4(f2bf(f.x), f2bf(f.y), f2bf(f.z), f2bf(f.w));
        *(ushort4*)(As + (size_t)r * kLdA + k4 * 4) = o;
    }
    __syncthreads();

    floatx4 acc[2][4] = {};
    const short8* BpV = (const short8*)Bp;

    // ---- phase 1: content @ proj_w^T  (kc 8..17) ----
    #pragma unroll
    for (int kc = 8; kc < 18; ++kc) {
        const short8* bp = BpV + (size_t)(kc * 32 + wv * 4) * 64 + lane;
        short8 b0 = bp[0], b1 = bp[64], b2 = bp[128], b3 = bp[192];
        short8 a[2];
        #pragma unroll
        for (int rt = 0; rt < 2; ++rt)
            a[rt] = *(const short8*)(As + (size_t)(rt * 16 + l15) * kLdA + kc * 32 + quad * 8);
        #pragma unroll
        for (int rt = 0; rt < 2; ++rt) {
            acc[rt][0] = __builtin_amdgcn_mfma_f32_16x16x32_bf16(a[rt], b0, acc[rt][0], 0, 0, 0);
            acc[rt][1] = __builtin_amdgcn_mfma_f32_16x16x32_bf16(a[rt], b1, acc[rt][1], 0, 0, 0);
            acc[rt][2] = __builtin_amdgcn_mfma_f32_16x16x32_bf16(a[rt], b2, acc[rt][2], 0, 0, 0);
            acc[rt][3] = __builtin_amdgcn_mfma_f32_16x16x32_bf16(a[rt], b3, acc[rt][3], 0, 0, 0);
        }
    }

    const int colbase = wv * 64 + l15;
    float pb[4], pg[4], pbt[4], eb[4];
    #pragma unroll
    for (int ct = 0; ct < 4; ++ct) {
        int c = colbase + ct * 16;
        pb[ct]  = proj_b[c];
        pg[ct]  = proj_g[c];
        pbt[ct] = proj_beta[c];
        eb[ct]  = ee_b[c];
    }

    // leaky + partial LN stats
    float s8[8], q8[8];
    #pragma unroll
    for (int rt = 0; rt < 2; ++rt) {
        #pragma unroll
        for (int i = 0; i < 4; ++i) {
            float s = 0.f, q = 0.f;
            #pragma unroll
            for (int ct = 0; ct < 4; ++ct) {
                float c = acc[rt][ct][i] + pb[ct];
                c = (c >= 0.f) ? c : 0.1f * c;
                acc[rt][ct][i] = c;
                s += c; q = fmaf(c, c, q);
            }
            s8[rt * 4 + i] = s; q8[rt * 4 + i] = q;
        }
    }
    #pragma unroll
    for (int idx = 0; idx < 8; ++idx) {
        #pragma unroll
        for (int m = 1; m < 16; m <<= 1) {
            s8[idx] += __shfl_xor(s8[idx], m);
            q8[idx] += __shfl_xor(q8[idx], m);
        }
    }
    if (l15 == 0) {
        #pragma unroll
        for (int rt = 0; rt < 2; ++rt)
            #pragma unroll
            for (int i = 0; i < 4; ++i) {
                int rl = rt * 16 + quad * 4 + i;
                redS[wv][rl] = s8[rt * 4 + i];
                redQ[wv][rl] = q8[rt * 4 + i];
            }
    }
    __syncthreads();
    if (t < kRowsN) {
        float s = 0.f, q = 0.f;
        #pragma unroll
        for (int w = 0; w < 8; ++w) { s += redS[w][t]; q += redQ[w][t]; }
        float m   = s * (1.f / 512.f);
        float var = q * (1.f / 512.f) - m * m;
        meanv[t] = m;
        rstdv[t] = rsqrtf(var + 1e-5f);
    }
    __syncthreads();

    // acc := normalized-content + ee_b  (emb MFMAs accumulate on top)
    #pragma unroll
    for (int rt = 0; rt < 2; ++rt) {
        #pragma unroll
        for (int i = 0; i < 4; ++i) {
            int rl = rt * 16 + quad * 4 + i;
            float m = meanv[rl], rs = rstdv[rl];
            #pragma unroll
            for (int ct = 0; ct < 4; ++ct)
                acc[rt][ct][i] = (acc[rt][ct][i] - m) * rs * pg[ct] + pbt[ct] + eb[ct];
        }
    }

    // ---- phase 2: emb @ ee_w^T  (kc 0..7) ----
    #pragma unroll
    for (int kc = 0; kc < 8; ++kc) {
        const short8* bp = BpV + (size_t)(kc * 32 + wv * 4) * 64 + lane;
        short8 b0 = bp[0], b1 = bp[64], b2 = bp[128], b3 = bp[192];
        short8 a[2];
        #pragma unroll
        for (int rt = 0; rt < 2; ++rt)
            a[rt] = *(const short8*)(As + (size_t)(rt * 16 + l15) * kLdA + kc * 32 + quad * 8);
        #pragma unroll
        for (int rt = 0; rt < 2; ++rt) {
            acc[rt][0] = __builtin_amdgcn_mfma_f32_16x16x32_bf16(a[rt], b0, acc[rt][0], 0, 0, 0);
            acc[rt][1] = __builtin_amdgcn_mfma_f32_16x16x32_bf16(a[rt], b1, acc[rt][1], 0, 0, 0);
            acc[rt][2] = __builtin_amdgcn_mfma_f32_16x16x32_bf16(a[rt], b2, acc[rt][2], 0, 0, 0);
            acc[rt][3] = __builtin_amdgcn_mfma_f32_16x16x32_bf16(a[rt], b3, acc[rt][3], 0, 0, 0);
        }
    }

    // ---- row norm ----
    #pragma unroll
    for (int rt = 0; rt < 2; ++rt) {
        #pragma unroll
        for (int i = 0; i < 4; ++i) {
            float psq = 0.f;
            #pragma unroll
            for (int ct = 0; ct < 4; ++ct)
                psq = fmaf(acc[rt][ct][i], acc[rt][ct][i], psq);
            q8[rt * 4 + i] = psq;
        }
    }
    #pragma unroll
    for (int idx = 0; idx < 8; ++idx)
        #pragma unroll
        for (int m = 1; m < 16; m <<= 1)
            q8[idx] += __shfl_xor(q8[idx], m);
    if (l15 == 0) {
        #pragma unroll
        for (int rt = 0; rt < 2; ++rt)
            #pragma unroll
            for (int i = 0; i < 4; ++i)
                redS[wv][rt * 16 + quad * 4 + i] = q8[rt * 4 + i];
    }
    __syncthreads();
    if (t < kRowsN) {
        float s = 0.f;
        #pragma unroll
        for (int w = 0; w < 8; ++w) s += redS[w][t];
        rowinv[t] = 1.f / fmaxf(sqrtf(s), 1e-5f);
    }
    __syncthreads();

    #pragma unroll
    for (int rt = 0; rt < 2; ++rt) {
        #pragma unroll
        for (int i = 0; i < 4; ++i) {
            int rl = rt * 16 + quad * 4 + i;
            int grow = row0 + rl;
            if (grow < n) {
                float inv = rowinv[rl];
                ushort* dB = outB + (size_t)grow * ldh + colbase;
                #pragma unroll
                for (int ct = 0; ct < 4; ++ct) {
                    float v = acc[rt][ct][i] * inv;
                    dB[ct * 16] = f2bf(v);
                    if (outF) outF[(size_t)grow * ldh + colbase + ct * 16] = v;
                }
            }
        }
    }
}

// ---------------------------------------------------------------------------
// MFMA GEMM, bf16 A-operand: C = A(MxK,bf16) @ W^T + bias, fused epilogue.
// 48 rows x 512 cols per block. EPI: 0=plain->bf16  1=gelu->bf16
// 2=residual(fp32)+LayerNorm -> fp32 Cf AND bf16 Cb (N==512, nb==0)
// ---------------------------------------------------------------------------
__device__ inline float gelu_exact(float x) {
    return 0.5f * x * (1.f + erff(x * 0.70710678118654752f));
}

template<int EPI>
__global__ __launch_bounds__(512, 2) void gemm_mfma(
    const ushort* __restrict__ A, int lda,
    const ushort* __restrict__ Bp, const float* __restrict__ bias,
    ushort* __restrict__ Cb, float* __restrict__ Cf, int ldc,
    const float* __restrict__ resid,
    const float* __restrict__ lng, const float* __restrict__ lnb,
    int M, int K, int N)
{
    __shared__ __align__(16) ushort As[kRows * kLdG];      // 49920 B
    __shared__ float redS[8][kRows], redQ[8][kRows];
    __shared__ float meanv[kRows], rstdv[kRows];

    const int t    = threadIdx.x;
    const int lane = t & 63;
    const int wv   = t >> 6;
    const int quad = lane >> 4;
    const int l15  = lane & 15;
    const int row0 = blockIdx.x * kRows;
    const int nb   = blockIdx.y;
    const int NT   = N >> 4;

    floatx4 acc[3][4] = {};
    const short8* BpV = (const short8*)Bp;

    for (int k0 = 0; k0 < K; k0 += 512) {
        // stage A chunk (48 x 512) bf16 direct: 3072 x 16B slots = 6*512
        #pragma unroll
        for (int it = 0; it < 6; ++it) {
            int flat = it * 512 + t;
            int r  = flat >> 6;          // 64 slots per row
            int k8 = flat & 63;
            int row = row0 + r; if (row >= M) row = M - 1;
            short8 v = *(const short8*)(A + (size_t)row * lda + k0 + k8 * 8);
            *(short8*)(As + (size_t)r * kLdG + k8 * 8) = v;
        }
        __syncthreads();
        const int g0 = k0 >> 5;
        #pragma unroll
        for (int kc = 0; kc < 16; ++kc) {
            const short8* bp = BpV + ((size_t)(g0 + kc) * NT + nb * 32 + wv * 4) * 64 + lane;
            short8 b0 = bp[0], b1 = bp[64], b2 = bp[128], b3 = bp[192];
            short8 a[3];
            #pragma unroll
            for (int rt = 0; rt < 3; ++rt)
                a[rt] = *(const short8*)(As + (size_t)(rt * 16 + l15) * kLdG + kc * 32 + quad * 8);
            #pragma unroll
            for (int rt = 0; rt < 3; ++rt) {
                acc[rt][0] = __builtin_amdgcn_mfma_f32_16x16x32_bf16(a[rt], b0, acc[rt][0], 0, 0, 0);
                acc[rt][1] = __builtin_amdgcn_mfma_f32_16x16x32_bf16(a[rt], b1, acc[rt][1], 0, 0, 0);
                acc[rt][2] = __builtin_amdgcn_mfma_f32_16x16x32_bf16(a[rt], b2, acc[rt][2], 0, 0, 0);
                acc[rt][3] = __builtin_amdgcn_mfma_f32_16x16x32_bf16(a[rt], b3, acc[rt][3], 0, 0, 0);
            }
        }
        __syncthreads();
    }

    const int colloc = wv * 64 + l15;           // 0..511 within col-block
    float b[4];
    #pragma unroll
    for (int ct = 0; ct < 4; ++ct) b[ct] = bias[nb * 512 + colloc + ct * 16];

    if constexpr (EPI == 0 || EPI == 1) {
        #pragma unroll
        for (int rt = 0; rt < 3; ++rt) {
            #pragma unroll
            for (int i = 0; i < 4; ++i) {
                int row = row0 + rt * 16 + quad * 4 + i;
                if (row < M) {
                    ushort* dst = Cb + (size_t)row * ldc + nb * 512 + colloc;
                    #pragma unroll
                    for (int ct = 0; ct < 4; ++ct) {
                        float v = acc[rt][ct][i] + b[ct];
                        if (EPI == 1) v = gelu_exact(v);
                        dst[ct * 16] = f2bf(v);
                    }
                }
            }
        }
    } else {
        float lg[4], lb[4];
        #pragma unroll
        for (int ct = 0; ct < 4; ++ct) {
            lg[ct] = lng[colloc + ct * 16];
            lb[ct] = lnb[colloc + ct * 16];
        }
        float s12[12], q12[12];
        #pragma unroll
        for (int rt = 0; rt < 3; ++rt) {
            #pragma unroll
            for (int i = 0; i < 4; ++i) {
                int rl = rt * 16 + quad * 4 + i;
                int row = row0 + rl; if (row >= M) row = M - 1;
                const float* rr = resid + (size_t)row * 512 + colloc;
                float s = 0.f, q = 0.f;
                #pragma unroll
                for (int ct = 0; ct < 4; ++ct) {
                    float h = acc[rt][ct][i] + b[ct] + rr[ct * 16];
                    acc[rt][ct][i] = h;
                    s += h; q = fmaf(h, h, q);
                }
                s12[rt * 4 + i] = s; q12[rt * 4 + i] = q;
            }
        }
        #pragma unroll
        for (int idx = 0; idx < 12; ++idx) {
            #pragma unroll
            for (int m = 1; m < 16; m <<= 1) {
                s12[idx] += __shfl_xor(s12[idx], m);
                q12[idx] += __shfl_xor(q12[idx], m);
            }
        }
        if (l15 == 0) {
            #pragma unroll
            for (int rt = 0; rt < 3; ++rt)
                #pragma unroll
                for (int i = 0; i < 4; ++i) {
                    int rl = rt * 16 + quad * 4 + i;
                    redS[wv][rl] = s12[rt * 4 + i];
                    redQ[wv][rl] = q12[rt * 4 + i];
                }
        }
        __syncthreads();
        if (t < kRows) {
            float s = 0.f, q = 0.f;
            #pragma unroll
            for (int w = 0; w < 8; ++w) { s += redS[w][t]; q += redQ[w][t]; }
            float m   = s * (1.f / 512.f);
            float var = q * (1.f / 512.f) - m * m;
            meanv[t] = m;
            rstdv[t] = rsqrtf(var + 1e-5f);
        }
        __syncthreads();
        #pragma unroll
        for (int rt = 0; rt < 3; ++rt) {
            #pragma unroll
            for (int i = 0; i < 4; ++i) {
                int rl = rt * 16 + quad * 4 + i;
                int row = row0 + rl;
                if (row < M) {
                    float m = meanv[rl], rs = rstdv[rl];
                    float*  dF = Cf + (size_t)row * 512 + colloc;
                    ushort* dB = Cb + (size_t)row * 512 + colloc;
                    #pragma unroll
                    for (int ct = 0; ct < 4; ++ct) {
                        float v = (acc[rt][ct][i] - m) * rs * lg[ct] + lb[ct];
                        dF[ct * 16] = v;
                        dB[ct * 16] = f2bf(v);
                    }
                }
            }
        }
    }
}

// ---------------------------------------------------------------------------
// Merged 3-way GEMM (all K=512, N=512, bf16 A, bf16 C, plain epilogue).
// ---------------------------------------------------------------------------
__global__ __launch_bounds__(512, 2) void gemm3_mfma(
    const ushort* __restrict__ A0, const ushort* __restrict__ B0,
    const float* __restrict__ b0p, ushort* __restrict__ C0, int M0,
    const ushort* __restrict__ A1, const ushort* __restrict__ B1,
    const float* __restrict__ b1p, ushort* __restrict__ C1, int M1,
    const ushort* __restrict__ A2, const ushort* __restrict__ B2,
    const float* __restrict__ b2p, ushort* __restrict__ C2, int M2)
{
    __shared__ __align__(16) ushort As[kRows * kLdG];

    const int t    = threadIdx.x;
    const int lane = t & 63;
    const int wv   = t >> 6;
    const int quad = lane >> 4;
    const int l15  = lane & 15;

    const int g0 = (M0 + kRows - 1) / kRows;
    const int g1 = (M1 + kRows - 1) / kRows;
    int bx = blockIdx.x;
    const ushort* A; const ushort* Bw; const float* bias; ushort* C; int M;
    if (bx < g0)           { A = A0; Bw = B0; bias = b0p; C = C0; M = M0; }
    else if (bx < g0 + g1) { bx -= g0; A = A1; Bw = B1; bias = b1p; C = C1; M = M1; }
    else                   { bx -= g0 + g1; A = A2; Bw = B2; bias = b2p; C = C2; M = M2; }
    const int row0 = bx * kRows;

    floatx4 acc[3][4] = {};
    const short8* BpV = (const short8*)Bw;

    #pragma unroll
    for (int it = 0; it < 6; ++it) {
        int flat = it * 512 + t;
        int r  = flat >> 6;
        int k8 = flat & 63;
        int row = row0 + r; if (row >= M) row = M - 1;
        short8 v = *(const short8*)(A + (size_t)row * 512 + k8 * 8);
        *(short8*)(As + (size_t)r * kLdG + k8 * 8) = v;
    }
    __syncthreads();
    #pragma unroll
    for (int kc = 0; kc < 16; ++kc) {
        const short8* bp = BpV + ((size_t)kc * 32 + wv * 4) * 64 + lane;
        short8 b0 = bp[0], b1 = bp[64], b2 = bp[128], b3 = bp[192];
        short8 a[3];
        #pragma unroll
        for (int rt = 0; rt < 3; ++rt)
            a[rt] = *(const short8*)(As + (size_t)(rt * 16 + l15) * kLdG + kc * 32 + quad * 8);
        #pragma unroll
        for (int rt = 0; rt < 3; ++rt) {
            acc[rt][0] = __builtin_amdgcn_mfma_f32_16x16x32_bf16(a[rt], b0, acc[rt][0], 0, 0, 0);
            acc[rt][1] = __builtin_amdgcn_mfma_f32_16x16x32_bf16(a[rt], b1, acc[rt][1], 0, 0, 0);
            acc[rt][2] = __builtin_amdgcn_mfma_f32_16x16x32_bf16(a[rt], b2, acc[rt][2], 0, 0, 0);
            acc[rt][3] = __builtin_amdgcn_mfma_f32_16x16x32_bf16(a[rt], b3, acc[rt][3], 0, 0, 0);
        }
    }

    const int colloc = wv * 64 + l15;
    float b[4];
    #pragma unroll
    for (int ct = 0; ct < 4; ++ct) b[ct] = bias[colloc + ct * 16];
    #pragma unroll
    for (int rt = 0; rt < 3; ++rt) {
        #pragma unroll
        for (int i = 0; i < 4; ++i) {
            int row = row0 + rt * 16 + quad * 4 + i;
            if (row < M) {
                ushort* dst = C + (size_t)row * 512 + colloc;
                #pragma unroll
                for (int ct = 0; ct < 4; ++ct)
                    dst[ct * 16] = f2bf(acc[rt][ct][i] + b[ct]);
            }
        }
    }
}

// ---------------------------------------------------------------------------
// Vectorized gather/elementwise kernels: one wave64 per output row, short8
// (16 B/lane) loads, wave-shuffle reductions, 4 rows per 256-thread block.
// ---------------------------------------------------------------------------
__global__ __launch_bounds__(256) void agg_norm1_kernel(
    const ushort* __restrict__ h0, const int* __restrict__ esrc,
    ushort* __restrict__ h1cat)
{
    const int wv = threadIdx.x >> 6, lane = threadIdx.x & 63;
    const int i = blockIdx.x * 4 + wv;          // dst row (kN1 % 4 == 0)
    const int* ep = esrc + (size_t)i * kDeg;
    float s[8] = {};
    #pragma unroll
    for (int e = 0; e < kDeg; ++e) {
        short8 v = *(const short8*)(h0 + (size_t)ep[e] * 512 + lane * 8);
        #pragma unroll
        for (int j = 0; j < 8; ++j) s[j] += bf2f((ushort)v[j]);
    }
    #pragma unroll
    for (int j = 0; j < 8; ++j) s[j] *= 0.1f;
    size_t base = (size_t)i * 1024;
    short8 ov = *(const short8*)(h1cat + base + 512 + lane * 8);
    float o[8];
    float q = 0.f;
    #pragma unroll
    for (int j = 0; j < 8; ++j) {
        o[j] = bf2f((ushort)ov[j]);
        q = fmaf(s[j], s[j], q);
        q = fmaf(o[j], o[j], q);
    }
    #pragma unroll
    for (int m = 32; m > 0; m >>= 1) q += __shfl_xor(q, m);
    float inv = 1.f / fmaxf(sqrtf(q), 1e-5f);
    short8 ws, wo;
    #pragma unroll
    for (int j = 0; j < 8; ++j) {
        ws[j] = (short)f2bf(s[j] * inv);
        wo[j] = (short)f2bf(o[j] * inv);
    }
    *(short8*)(h1cat + base + lane * 8)       = ws;
    *(short8*)(h1cat + base + 512 + lane * 8) = wo;
}

__global__ __launch_bounds__(256) void agg2_kernel(
    const ushort* __restrict__ h1cat, const int* __restrict__ esrc,
    ushort* __restrict__ m2)
{
    const int wv = threadIdx.x >> 6, lane = threadIdx.x & 63;
    const int i = blockIdx.x * 4 + wv;          // dst row (kN2 % 4 == 0)
    const int* ep = esrc + (size_t)i * kDeg;
    float s0[8] = {}, s1[8] = {};
    #pragma unroll
    for (int e = 0; e < kDeg; ++e) {
        const ushort* hr = h1cat + (size_t)ep[e] * 1024 + lane * 8;
        short8 va = *(const short8*)hr;
        short8 vb = *(const short8*)(hr + 512);
        #pragma unroll
        for (int j = 0; j < 8; ++j) {
            s0[j] += bf2f((ushort)va[j]);
            s1[j] += bf2f((ushort)vb[j]);
        }
    }
    size_t base = (size_t)i * 1024;
    short8 w0, w1;
    #pragma unroll
    for (int j = 0; j < 8; ++j) {
        w0[j] = (short)f2bf(s0[j] * 0.1f);
        w1[j] = (short)f2bf(s1[j] * 0.1f);
    }
    *(short8*)(m2 + base + lane * 8)       = w0;
    *(short8*)(m2 + base + 512 + lane * 8) = w1;
}

// One wave per query row; lanes 0..31 = head0 cols [0,256), 32..63 = head1.
// Kb/Vb rows: 2i = memory slot 0, 2i+1 = slot 1.
__global__ __launch_bounds__(256) void attn_combine_kernel(
    const ushort* __restrict__ Q,
    const ushort* __restrict__ Kb, const ushort* __restrict__ Vb,
    ushort* __restrict__ O)
{
    const int wv = threadIdx.x >> 6, lane = threadIdx.x & 63;
    const int i = blockIdx.x * 4 + wv;          // query row (kN2 % 4 == 0)
    size_t base  = (size_t)i * 512;
    size_t base0 = (size_t)(2 * i) * 512;
    size_t base1 = base0 + 512;
    const int off = lane * 8;
    short8 qv = *(const short8*)(Q  + base  + off);
    short8 k0 = *(const short8*)(Kb + base0 + off);
    short8 k1 = *(const short8*)(Kb + base1 + off);
    float p0 = 0.f, p1 = 0.f;
    #pragma unroll
    for (int j = 0; j < 8; ++j) {
        float qf = bf2f((ushort)qv[j]);
        p0 = fmaf(qf, bf2f((ushort)k0[j]), p0);
        p1 = fmaf(qf, bf2f((ushort)k1[j]), p1);
    }
    #pragma unroll
    for (int m = 16; m > 0; m >>= 1) {          // reduce within 32-lane head
        p0 += __shfl_xor(p0, m);
        p1 += __shfl_xor(p1, m);
    }
    float s0 = p0 * 0.0625f, s1 = p1 * 0.0625f; // dh=256 -> 1/16
    float mx = fmaxf(s0, s1);
    float e0 = expf(s0 - mx), e1 = expf(s1 - mx);
    float d  = e0 + e1;
    float a0 = e0 / d, a1 = e1 / d;
    short8 v0 = *(const short8*)(Vb + base0 + off);
    short8 v1 = *(const short8*)(Vb + base1 + off);
    short8 w;
    #pragma unroll
    for (int j = 0; j < 8; ++j)
        w[j] = (short)f2bf(a0 * bf2f((ushort)v0[j]) + a1 * bf2f((ushort)v1[j]));
    *(short8*)(O + base + off) = w;
}

__global__ __launch_bounds__(256) void final_norm_kernel(
    const float* __restrict__ tgt, float* __restrict__ out)
{
    const int wv = threadIdx.x >> 6, lane = threadIdx.x & 63;
    const int i = blockIdx.x * 4 + wv;          // row (kN2 % 4 == 0)
    size_t base = (size_t)i * 512 + lane * 8;
    float4 a = *(const float4*)(tgt + base);
    float4 b = *(const float4*)(tgt + base + 4);
    float q = a.x*a.x + a.y*a.y + a.z*a.z + a.w*a.w
            + b.x*b.x + b.y*b.y + b.z*b.z + b.w*b.w;
    #pragma unroll
    for (int m = 32; m > 0; m >>= 1) q += __shfl_xor(q, m);
    float inv = 1.f / fmaxf(sqrtf(q), 1e-5f);
    a.x *= inv; a.y *= inv; a.z *= inv; a.w *= inv;
    b.x *= inv; b.y *= inv; b.z *= inv; b.w *= inv;
    *(float4*)(out + base)     = a;
    *(float4*)(out + base + 4) = b;
}

// ---------------------------------------------------------------------------
extern "C" void kernel_launch(void* const* d_in, const int* in_sizes, int n_in,
                              void* d_out, int out_size, void* d_ws, size_t ws_size,
                              hipStream_t stream)
{
    (void)in_sizes; (void)n_in; (void)out_size; (void)ws_size;
    const int*   nid0       = (const int*)d_in[0];
    const int*   nid1       = (const int*)d_in[1];
    const int*   nid2       = (const int*)d_in[2];
    const int*   esrc0      = (const int*)d_in[3];
    const int*   esrc1      = (const int*)d_in[5];
    const float* content0   = (const float*)d_in[7];
    const float* content1   = (const float*)d_in[8];
    const float* content2   = (const float*)d_in[9];
    const float* node_emb_w = (const float*)d_in[10];
    const float* ee_w       = (const float*)d_in[11];
    const float* ee_b       = (const float*)d_in[12];
    const float* proj_w     = (const float*)d_in[13];
    const float* proj_b     = (const float*)d_in[14];
    const float* proj_g     = (const float*)d_in[15];
    const float* proj_beta  = (const float*)d_in[16];
    const float* sa_in_w    = (const float*)d_in[17];
    const float* sa_in_b    = (const float*)d_in[18];
    const float* sa_out_w   = (const float*)d_in[19];
    const float* sa_out_b   = (const float*)d_in[20];
    const float* ca_in_w    = (const float*)d_in[21];
    const float* ca_in_b    = (const float*)d_in[22];
    const float* ca_out_w   = (const float*)d_in[23];
    const float* ca_out_b   = (const float*)d_in[24];
    const float* lin1_w     = (const float*)d_in[25];
    const float* lin1_b     = (const float*)d_in[26];
    const float* lin2_w     = (const float*)d_in[27];
    const float* lin2_b     = (const float*)d_in[28];
    const float* n1_g       = (const float*)d_in[29];
    const float* n1_b       = (const float*)d_in[30];
    const float* n2_g       = (const float*)d_in[31];
    const float* n2_b       = (const float*)d_in[32];
    const float* n3_g       = (const float*)d_in[33];
    const float* n3_b       = (const float*)d_in[34];

    float* ws = (float*)d_ws;
    size_t off = 0;
    ushort* h0b    = (ushort*)(ws + off); off += (size_t)kN0 * 512 / 2;
    ushort* h1catb = (ushort*)(ws + off); off += (size_t)kN1 * 1024 / 2;
    ushort* m2b    = (ushort*)(ws + off); off += (size_t)kN2 * 1024 / 2;
    float*  tgt    = ws + off;            off += (size_t)kN2 * 512;
    ushort* tgtb   = (ushort*)(ws + off); off += (size_t)kN2 * 512 / 2;
    ushort* Qbb    = (ushort*)(ws + off); off += (size_t)kN2 * 512 / 2;
    ushort* Kbb    = (ushort*)(ws + off); off += (size_t)2 * kN2 * 512 / 2;
    ushort* Vbb    = (ushort*)(ws + off); off += (size_t)2 * kN2 * 512 / 2;
    ushort* Obb    = (ushort*)(ws + off); off += (size_t)kN2 * 512 / 2;
    ushort* ffhb   = (ushort*)(ws + off); off += (size_t)kN2 * 2048 / 2;
    ushort* BpNode = (ushort*)(ws + off); off += 147456;           // 576*64*8 bf16
    ushort* Pw512  = (ushort*)(ws + off); off += 12 * 262144 / 2;  // 12 x 512x512
    ushort* Pl1    = (ushort*)(ws + off); off += 2 * 1048576 / 2;  // 2 x 2048x512
    ushort* Pl2    = (ushort*)(ws + off); off += 2 * 1048576 / 2;  // 2 x 512x2048

    dim3 blk(256);

    // ---- weight packing (4 launches) ----
    pack_node_w_kernel<<<dim3(144), blk, 0, stream>>>(ee_w, proj_w, BpNode);
    pack512_many_kernel<<<dim3(128, 12), blk, 0, stream>>>(
        sa_in_w, sa_out_w, ca_in_w, ca_out_w, Pw512);
    pack_generic_kernel<<<dim3(512, 2), blk, 0, stream>>>(
        lin1_w, (size_t)kFF * kD, Pl1, 1048576, kFF, kD);
    pack_generic_kernel<<<dim3(512, 2), blk, 0, stream>>>(
        lin2_w, (size_t)kD * kFF, Pl2, 1048576, kD, kFF);

    // ---- node_h (merged 3-segment dispatch, 2 blocks/CU) ----
    {
        int g0 = (kN0 + kRowsN - 1) / kRowsN;   // 3125
        int g1 = (kN1 + kRowsN - 1) / kRowsN;   // 625
        int g2 = (kN2 + kRowsN - 1) / kRowsN;   // 125
        node_h_mfma<<<dim3(g0 + g1 + g2), dim3(512), 0, stream>>>(
            nid0, content0, h0b, kN0,
            nid1, content1, h1catb + 512, kN1,
            nid2, content2, tgtb, tgt, kN2,
            node_emb_w, BpNode, ee_b, proj_b, proj_g, proj_beta);
    }

    agg_norm1_kernel<<<dim3(kN1 / 4), blk, 0, stream>>>(h0b, esrc0, h1catb);
    agg2_kernel<<<dim3(kN2 / 4), blk, 0, stream>>>(h1catb, esrc1, m2b);

    const int M   = kN2;
    const int gM  = (M + kRows - 1) / kRows;       // 84
    const int gM2 = (2 * M + kRows - 1) / kRows;   // 167
    dim3 blk512(512);
    for (int l = 0; l < 2; ++l) {
        const ushort* sa_v_p   = Pw512 + (size_t)(l * 6 + 0) * 262144;
        const ushort* sa_out_p = Pw512 + (size_t)(l * 6 + 1) * 262144;
        const ushort* ca_q_p   = Pw512 + (size_t)(l * 6 + 2) * 262144;
        const ushort* ca_k_p   = Pw512 + (size_t)(l * 6 + 3) * 262144;
        const ushort* ca_v_p   = Pw512 + (size_t)(l * 6 + 4) * 262144;
        const ushort* ca_out_p = Pw512 + (size_t)(l * 6 + 5) * 262144;
        const ushort* l1_p     = Pl1 + (size_t)l * 1048576;
        const ushort* l2_p     = Pl2 + (size_t)l * 1048576;
        const float* sa_b = sa_in_b + (size_t)l * 3 * kD;
        const float* saob = sa_out_b + (size_t)l * kD;
        const float* ca_b = ca_in_b + (size_t)l * 3 * kD;
        const float* caob = ca_out_b + (size_t)l * kD;
        const float* l1b = lin1_b + (size_t)l * kFF;
        const float* l2b = lin2_b + (size_t)l * kD;

        // merged: sa_v (tgtb), ca_k (m2b), ca_v (m2b) — all independent here
        gemm3_mfma<<<dim3(gM + gM2 + gM2), blk512, 0, stream>>>(
            tgtb, sa_v_p, sa_b + 2 * kD, Qbb, M,
            m2b,  ca_k_p, ca_b + kD,     Kbb, 2 * M,
            m2b,  ca_v_p, ca_b + 2 * kD, Vbb, 2 * M);

        // self-attention (seq len 1 => o = v-projection)
        gemm_mfma<2><<<dim3(gM, 1), blk512, 0, stream>>>(
            Qbb, 512, sa_out_p, saob, tgtb, tgt, 512,
            tgt, n1_g + l * kD, n1_b + l * kD, M, 512, 512);

        // cross-attention
        gemm_mfma<0><<<dim3(gM, 1), blk512, 0, stream>>>(
            tgtb, 512, ca_q_p, ca_b, Qbb, nullptr, 512,
            nullptr, nullptr, nullptr, M, 512, 512);
        attn_combine_kernel<<<dim3(M / 4), blk, 0, stream>>>(Qbb, Kbb, Vbb, Obb);
        gemm_mfma<2><<<dim3(gM, 1), blk512, 0, stream>>>(
            Obb, 512, ca_out_p, caob, tgtb, tgt, 512,
            tgt, n2_g + l * kD, n2_b + l * kD, M, 512, 512);

        // feed-forward
        gemm_mfma<1><<<dim3(gM, 4), blk512, 0, stream>>>(
            tgtb, 512, l1_p, l1b, ffhb, nullptr, 2048,
            nullptr, nullptr, nullptr, M, 512, 2048);
        gemm_mfma<2><<<dim3(gM, 1), blk512, 0, stream>>>(
            ffhb, 2048, l2_p, l2b, tgtb, tgt, 512,
            tgt, n3_g + l * kD, n3_b + l * kD, M, 2048, 512);
    }

    final_norm_kernel<<<dim3(kN2 / 4), blk, 0, stream>>>(tgt, (float*)d_out);
}